// Round 4
// baseline (1103.655 us; speedup 1.0000x reference)
//
#include <hip/hip_runtime.h>

#define C_N 64
#define I_N 64
#define R_N 36
#define L_N 40
#define D_N 1024
#define S_N 256

#define P_LD 40    // p row stride (shorts): 80 B rows; 2-way-only LDS bank aliasing
#define SIM_LD 40  // sim chunk row stride (shorts)

// ws layout (shorts):
#define OFF_CAP 2359296               // img end
#define OFF_WT  4980736               // cap end: Wt [s][d]
#define OFF_IMT 5242880               // wt end: img_t [i][d][r48]
#define OFF_SLK 8126464               // img_t end: 64 zero shorts (k-overread slack)

typedef float f4 __attribute__((ext_vector_type(4)));
typedef short s16x8 __attribute__((ext_vector_type(8)));
typedef short s16x4 __attribute__((ext_vector_type(4)));
typedef unsigned u32x2 __attribute__((ext_vector_type(2)));

__device__ __forceinline__ unsigned short f2bs(float f) {
    union { float f; unsigned u; } v; v.f = f;
    unsigned r = v.u + 0x7FFFu + ((v.u >> 16) & 1u);
    return (unsigned short)(r >> 16);
}
__device__ __forceinline__ float bs2f(unsigned short s) {
    union { unsigned u; float f; } v; v.u = ((unsigned)s) << 16;
    return v.f;
}
// RTNE pack of two f32 -> {lo16=bf16(a), hi16=bf16(b)}; same rounding as f2bs.
__device__ __forceinline__ unsigned cvtpk(float a, float b) {
    unsigned r;
    asm("v_cvt_pk_bf16_f32 %0, %1, %2" : "=v"(r) : "v"(a), "v"(b));
    return r;
}

// ---------------- K0: linear converts ----------------
__global__ void k_convert(const float* __restrict__ img, const float* __restrict__ cap,
                          const float* __restrict__ W, unsigned short* __restrict__ ws) {
    int t = blockIdx.x * 256 + threadIdx.x;
    if (t < I_N * R_N * D_N) ws[t] = f2bs(img[t]);
    if (t < C_N * L_N * D_N) ws[OFF_CAP + t] = f2bs(cap[t]);
    if (t < D_N * S_N) {                       // W[d][s] -> Wt[s][d]
        int d = t >> 8, s = t & 255;
        ws[OFF_WT + s * D_N + d] = f2bs(W[t]);
    }
    if (t < 64) ws[OFF_SLK + t] = 0;
}

// ---------------- K0b: img [i][r][d] f32 -> imt [i][d][r48] bf16, LDS-tiled ----------
__global__ __launch_bounds__(256)
void k_imt(const float* __restrict__ img, unsigned short* __restrict__ imt) {
    __shared__ unsigned short t[64][50];
    const int i = blockIdx.y, d0 = blockIdx.x * 64;
    const int tid = threadIdx.x;
    #pragma unroll
    for (int it = 0; it < 9; ++it) {           // 36 r x 64 dc
        int e = it * 256 + tid;
        int r = e >> 6, dc = e & 63;
        t[dc][r] = f2bs(img[((size_t)i * R_N + r) * D_N + d0 + dc]);
    }
    #pragma unroll
    for (int it = 0; it < 3; ++it) {           // zero r 36..47
        int e = it * 256 + tid;
        t[e & 63][36 + (e >> 6)] = 0;
    }
    __syncthreads();
    #pragma unroll
    for (int it = 0; it < 6; ++it) {           // 64 rows x 24 dwords, contiguous
        int e = it * 256 + tid;
        int dc = e / 24, wd = e - dc * 24;
        unsigned v = (unsigned)t[dc][2 * wd] | ((unsigned)t[dc][2 * wd + 1] << 16);
        ((unsigned*)imt)[(size_t)(i * D_N + d0 + dc) * 24 + wd] = v;
    }
}

// ---------------- FUSED: GEMM1 + softmax + GEMM2 + GEMM3, no sim materialization.
// 4 waves per (c,i) pair, split on GEMM3's s dim (64 s each). GEMM1/softmax/GEMM2
// duplicated per wave (keeps waves independent; VALU has 5x headroom). Per d-chunk
// (32 d): sim computed in registers -> bounced through a 3.2KB LDS slot to repack
// into an MFMA A-fragment -> accumulated into this wave's 40x64 GEMM3 acc.
// Block = 8 waves = 2 c x 4 s-quarters sharing image i. ONE __syncthreads (final
// cross-s l2norm exchange). Grid 2048; XCD tiling = 16 images x 32 captions/XCD
// (proven: FETCH 38MB). Round-2 lesson: don't force VGPR below ~128 (spills).
__global__ __launch_bounds__(512, 4)
void k_fused(const unsigned short* __restrict__ img_b,
             const unsigned short* __restrict__ cap_b,
             const unsigned short* __restrict__ img_t,
             const unsigned short* __restrict__ wt,
             const int* __restrict__ cap_lens,
             const float* __restrict__ bias,
             float* __restrict__ out) {
    __shared__ __align__(16) unsigned short s_p[8][L_N * P_LD];     // 25600 B
    __shared__ __align__(16) unsigned short s_sim[8][L_N * SIM_LD]; // 25600 B
    __shared__ float s_ss[8][48];                                   // 1536 B

    const int x = blockIdx.x, m = blockIdx.y;        // linear id n = m*8+x; XCD = x
    const int i   = ((x & 3) << 4) | (m >> 4);       // 16 images per XCD
    const int duo = ((x >> 2) << 4) | (m & 15);      // 16 c-duos (32 c) per XCD
    const int wave = threadIdx.x >> 6, lane = threadIdx.x & 63;
    const int cw = wave >> 2, sq = wave & 3;         // c-in-duo, s-quarter
    const int c = duo * 2 + cw;
    const int pair = c * I_N + i;
    const int q = lane >> 4, ln16 = lane & 15;

    const unsigned short* ai = img_b + i * (R_N * D_N);          // GEMM1 A (m=r)
    const unsigned short* bc = cap_b + c * (L_N * D_N);          // GEMM1 B (n=l), sim cap
    const unsigned short* imtc = img_t + (size_t)i * D_N * 48;   // GEMM2 A (m=d,k=r)
    unsigned short* sp = &s_p[wave][0];
    unsigned short* sps = &s_sim[wave][0];

    // zero own p slot (covers k-pad cols 36..39)
    for (int k = lane; k < L_N * P_LD / 2; k += 64) ((unsigned*)sp)[k] = 0;

    // ---- GEMM1: attn[r][l], full K=1024 ----
    f4 acc[3][3] = {};
    #pragma unroll 4
    for (int ks = 0; ks < 32; ++ks) {
        const int kb = ks * 32 + q * 8;
        s16x8 af[3], bf[3];
        af[0] = *(const s16x8*)(ai + ln16 * D_N + kb);
        af[1] = *(const s16x8*)(ai + (16 + ln16) * D_N + kb);
        af[2] = (ln16 < 4) ? *(const s16x8*)(ai + (32 + ln16) * D_N + kb) : (s16x8)0;
        bf[0] = *(const s16x8*)(bc + ln16 * D_N + kb);
        bf[1] = *(const s16x8*)(bc + (16 + ln16) * D_N + kb);
        bf[2] = (ln16 < 8) ? *(const s16x8*)(bc + (32 + ln16) * D_N + kb) : (s16x8)0;
        #pragma unroll
        for (int mt = 0; mt < 3; ++mt)
            #pragma unroll
            for (int nt = 0; nt < 3; ++nt)
                acc[mt][nt] = __builtin_amdgcn_mfma_f32_16x16x32_bf16(af[mt], bf[nt], acc[mt][nt], 0, 0, 0);
    }

    // ---- leaky relu ----
    #pragma unroll
    for (int mt = 0; mt < 3; ++mt)
        #pragma unroll
        for (int nt = 0; nt < 3; ++nt)
            #pragma unroll
            for (int j = 0; j < 4; ++j) {
                float v = acc[mt][nt][j];
                acc[mt][nt][j] = (v > 0.f) ? v : 0.1f * v;
            }
    // ---- l2norm over words l per region row r ----
    #pragma unroll
    for (int mt = 0; mt < 3; ++mt)
        #pragma unroll
        for (int j = 0; j < 4; ++j) {
            float ss = 0.f;
            #pragma unroll
            for (int nt = 0; nt < 3; ++nt) ss += acc[mt][nt][j] * acc[mt][nt][j];
            #pragma unroll
            for (int o = 1; o < 16; o <<= 1) ss += __shfl_xor(ss, o, 64);
            float inv = 1.f / (sqrtf(ss) + 1e-8f);
            #pragma unroll
            for (int nt = 0; nt < 3; ++nt) acc[mt][nt][j] *= inv;
        }
    // ---- softmax over r per word l; packed 8B stores p[l][r] to LDS ----
    #pragma unroll
    for (int nt = 0; nt < 3; ++nt) {
        const int l = nt * 16 + ln16;
        float mx = -1e30f;
        #pragma unroll
        for (int mt = 0; mt < 3; ++mt)
            #pragma unroll
            for (int j = 0; j < 4; ++j) {
                int r = mt * 16 + q * 4 + j;
                if (r < R_N) mx = fmaxf(mx, 9.f * acc[mt][nt][j]);
            }
        mx = fmaxf(mx, __shfl_xor(mx, 16, 64));
        mx = fmaxf(mx, __shfl_xor(mx, 32, 64));
        float sum = 0.f;
        #pragma unroll
        for (int mt = 0; mt < 3; ++mt)
            #pragma unroll
            for (int j = 0; j < 4; ++j) {
                int r = mt * 16 + q * 4 + j;
                float e = (r < R_N) ? __expf(9.f * acc[mt][nt][j] - mx) : 0.f;
                acc[mt][nt][j] = e;
                sum += e;
            }
        sum += __shfl_xor(sum, 16, 64);
        sum += __shfl_xor(sum, 32, 64);
        float inv = 1.f / sum;
        if (l < L_N) {
            #pragma unroll
            for (int mt = 0; mt < 3; ++mt) {
                if (mt < 2 || q == 0) {        // r-base = mt*16+q*4; rows >=36 skipped
                    u32x2 pv;
                    pv[0] = cvtpk(acc[mt][nt][0] * inv, acc[mt][nt][1] * inv);
                    pv[1] = cvtpk(acc[mt][nt][2] * inv, acc[mt][nt][3] * inv);
                    *(u32x2*)(sp + l * P_LD + mt * 16 + q * 4) = pv;
                }
            }
        }
    }
    // same-wave DS ordering: reads below see the writes (no barrier needed).

    // ---- GEMM2 p-fragments (B operand [n=l][k=r]); predicated for 40x40 slot ----
    s16x8 paf[3][2];
    #pragma unroll
    for (int nl = 0; nl < 3; ++nl)
        #pragma unroll
        for (int ks = 0; ks < 2; ++ks) {
            const bool live = (nl < 2 || ln16 < 8) && (ks == 0 || q == 0);
            paf[nl][ks] = live ? *(const s16x8*)(sp + (nl * 16 + ln16) * P_LD + ks * 32 + q * 8)
                               : (s16x8)0;
        }

    // ---- GEMM2 pass 1: wc sumsq over all d (for wc l2norm) ----
    float rs[3] = {};
    #pragma unroll 2
    for (int ch = 0; ch < 32; ++ch) {
        f4 a2[2][3] = {};
        #pragma unroll
        for (int ks = 0; ks < 2; ++ks) {
            const int kb = ks * 32 + q * 8;
            #pragma unroll
            for (int md = 0; md < 2; ++md) {
                const int drow = ch * 32 + md * 16 + ln16;
                s16x8 afr = *(const s16x8*)(imtc + drow * 48 + kb);
                #pragma unroll
                for (int nl = 0; nl < 3; ++nl)
                    a2[md][nl] = __builtin_amdgcn_mfma_f32_16x16x32_bf16(afr, paf[nl][ks], a2[md][nl], 0, 0, 0);
            }
        }
        #pragma unroll
        for (int md = 0; md < 2; ++md)
            #pragma unroll
            for (int nl = 0; nl < 3; ++nl)
                #pragma unroll
                for (int j = 0; j < 4; ++j)
                    rs[nl] += a2[md][nl][j] * a2[md][nl][j];
    }
    float inv2[3];
    #pragma unroll
    for (int nl = 0; nl < 3; ++nl) {
        float s = rs[nl];
        s += __shfl_xor(s, 16, 64);
        s += __shfl_xor(s, 32, 64);
        inv2[nl] = 1.f / (sqrtf(s) + 1e-8f);
    }

    // ---- GEMM2 pass 2 fused with GEMM3: per 32-d chunk, sim -> LDS -> A-frag ----
    const unsigned short* wq = wt + (size_t)(sq * 64) * D_N;   // this wave's s-quarter
    f4 acc3[3][4] = {};
    #pragma unroll 1
    for (int ch = 0; ch < 32; ++ch) {
        // recompute wc chunk
        f4 a2[2][3] = {};
        #pragma unroll
        for (int ks = 0; ks < 2; ++ks) {
            const int kb = ks * 32 + q * 8;
            #pragma unroll
            for (int md = 0; md < 2; ++md) {
                const int drow = ch * 32 + md * 16 + ln16;
                s16x8 afr = *(const s16x8*)(imtc + drow * 48 + kb);
                #pragma unroll
                for (int nl = 0; nl < 3; ++nl)
                    a2[md][nl] = __builtin_amdgcn_mfma_f32_16x16x32_bf16(afr, paf[nl][ks], a2[md][nl], 0, 0, 0);
            }
        }
        // sim = (wc*inv - cap)^2 -> bf16 -> own LDS chunk [l][d32]
        #pragma unroll
        for (int nl = 0; nl < 3; ++nl) {
            if (nl < 2 || ln16 < 8) {
                const int l = nl * 16 + ln16;
                const float iv = inv2[nl];
                #pragma unroll
                for (int md = 0; md < 2; ++md) {
                    const int db = ch * 32 + md * 16 + q * 4;   // 4 consecutive d
                    const s16x4 cv = *(const s16x4*)(bc + l * D_N + db);
                    float d0 = a2[md][nl][0] * iv - bs2f((unsigned short)cv[0]);
                    float d1 = a2[md][nl][1] * iv - bs2f((unsigned short)cv[1]);
                    float d2 = a2[md][nl][2] * iv - bs2f((unsigned short)cv[2]);
                    float d3 = a2[md][nl][3] * iv - bs2f((unsigned short)cv[3]);
                    u32x2 sv;
                    sv[0] = cvtpk(d0 * d0, d1 * d1);
                    sv[1] = cvtpk(d2 * d2, d3 * d3);
                    *(u32x2*)(sps + l * SIM_LD + md * 16 + q * 4) = sv;
                }
            }
        }
        // GEMM3: acc3[l][s] += sim_chunk[l][d32] . Wt[s][d32]
        s16x8 af3[3];
        #pragma unroll
        for (int mt = 0; mt < 3; ++mt) {
            const int l = mt * 16 + ln16;
            af3[mt] = (mt < 2 || ln16 < 8) ? *(const s16x8*)(sps + l * SIM_LD + q * 8)
                                           : (s16x8)0;
        }
        s16x8 bf3[4];
        #pragma unroll
        for (int nt = 0; nt < 4; ++nt)
            bf3[nt] = *(const s16x8*)(wq + (size_t)(nt * 16 + ln16) * D_N + ch * 32 + q * 8);
        #pragma unroll
        for (int mt = 0; mt < 3; ++mt)
            #pragma unroll
            for (int nt = 0; nt < 4; ++nt)
                acc3[mt][nt] = __builtin_amdgcn_mfma_f32_16x16x32_bf16(af3[mt], bf3[nt], acc3[mt][nt], 0, 0, 0);
    }

    // ---- epilogue: +bias, relu, row sumsq (this s-quarter), cross-wave exchange ----
    float bv[4];
    #pragma unroll
    for (int nt = 0; nt < 4; ++nt) bv[nt] = bias[sq * 64 + nt * 16 + ln16];
    #pragma unroll
    for (int mt = 0; mt < 3; ++mt)
        #pragma unroll
        for (int j = 0; j < 4; ++j) {
            float s = 0.f;
            #pragma unroll
            for (int nt = 0; nt < 4; ++nt) {
                float v = acc3[mt][nt][j] + bv[nt];
                v = fmaxf(v, 0.f);
                acc3[mt][nt][j] = v;
                s += v * v;
            }
            #pragma unroll
            for (int o = 1; o < 16; o <<= 1) s += __shfl_xor(s, o, 64);
            if (ln16 == 0) s_ss[wave][mt * 16 + q * 4 + j] = s;
        }
    __syncthreads();
    const int len = cap_lens[c];
    float* op = out + (size_t)pair * L_N * S_N + sq * 64;
    #pragma unroll
    for (int mt = 0; mt < 3; ++mt)
        #pragma unroll
        for (int j = 0; j < 4; ++j) {
            const int l = mt * 16 + q * 4 + j;
            if (l < L_N) {
                float tot = s_ss[(cw << 2) + 0][l] + s_ss[(cw << 2) + 1][l]
                          + s_ss[(cw << 2) + 2][l] + s_ss[(cw << 2) + 3][l];
                float inv = (l < len) ? 1.f / (sqrtf(tot) + 1e-8f) : 0.f;
                #pragma unroll
                for (int nt = 0; nt < 4; ++nt)
                    __builtin_nontemporal_store(acc3[mt][nt][j] * inv,
                        op + (size_t)l * S_N + nt * 16 + ln16);
            }
        }
}

extern "C" void kernel_launch(void* const* d_in, const int* in_sizes, int n_in,
                              void* d_out, int out_size, void* d_ws, size_t ws_size,
                              hipStream_t stream) {
    const float* img  = (const float*)d_in[0];
    const float* cap  = (const float*)d_in[1];
    const int*   lens = (const int*)d_in[2];
    const float* W    = (const float*)d_in[5];
    const float* bias = (const float*)d_in[6];
    float* out = (float*)d_out;
    unsigned short* ws = (unsigned short*)d_ws;

    k_convert<<<10240, 256, 0, stream>>>(img, cap, W, ws);
    dim3 gridT(16, I_N);
    k_imt<<<gridT, 256, 0, stream>>>(img, ws + OFF_IMT);

    dim3 gridF(8, 256);   // 2048 blocks; (x,m) -> (i, c-duo) XCD-tile remap
    k_fused<<<gridF, 512, 0, stream>>>(ws, ws + OFF_CAP, ws + OFF_IMT, ws + OFF_WT,
                                       lens, bias, out);
}

// Round 5
// 643.494 us; speedup vs baseline: 1.7151x; 1.7151x over previous
//
#include <hip/hip_runtime.h>

#define C_N 64
#define I_N 64
#define R_N 36
#define L_N 40
#define D_N 1024
#define S_N 256

#define P_LD 40   // p row stride (shorts): 80 B rows; predicated frags cover pads

// ws layout (shorts):
#define OFF_CAP 2359296               // img end
#define OFF_WT  4980736               // cap end: Wt [s][d]
#define OFF_IMT 5242880               // wt end: img_t [i][d][r48]
#define OFF_SLK 8126464               // img_t end: 64 zero shorts (k-overread slack)
#define OFF_SIM 8388672               // sim [pair*40 + l][1024] bf16
#define M_ALL   (C_N * I_N * L_N)

typedef float f4 __attribute__((ext_vector_type(4)));
typedef short s16x8 __attribute__((ext_vector_type(8)));
typedef short s16x4 __attribute__((ext_vector_type(4)));
typedef unsigned u32x2 __attribute__((ext_vector_type(2)));

__device__ __forceinline__ unsigned short f2bs(float f) {
    union { float f; unsigned u; } v; v.f = f;
    unsigned r = v.u + 0x7FFFu + ((v.u >> 16) & 1u);
    return (unsigned short)(r >> 16);
}
__device__ __forceinline__ float bs2f(unsigned short s) {
    union { unsigned u; float f; } v; v.u = ((unsigned)s) << 16;
    return v.f;
}
__device__ __forceinline__ void async16(const unsigned short* g, unsigned short* l) {
    __builtin_amdgcn_global_load_lds(
        (const __attribute__((address_space(1))) unsigned int*)g,
        (__attribute__((address_space(3))) unsigned int*)l, 16, 0, 0);
}

// ---------------- K0: linear converts ----------------
__global__ void k_convert(const float* __restrict__ img, const float* __restrict__ cap,
                          const float* __restrict__ W, unsigned short* __restrict__ ws) {
    int t = blockIdx.x * 256 + threadIdx.x;
    if (t < I_N * R_N * D_N) ws[t] = f2bs(img[t]);
    if (t < C_N * L_N * D_N) ws[OFF_CAP + t] = f2bs(cap[t]);
    if (t < D_N * S_N) {                       // W[d][s] -> Wt[s][d]
        int d = t >> 8, s = t & 255;
        ws[OFF_WT + s * D_N + d] = f2bs(W[t]);
    }
    if (t < 64) ws[OFF_SLK + t] = 0;
}

// ---------------- K0b: img [i][r][d] f32 -> imt [i][d][r48] bf16, LDS-tiled ----------
__global__ __launch_bounds__(256)
void k_imt(const float* __restrict__ img, unsigned short* __restrict__ imt) {
    __shared__ unsigned short t[64][50];
    const int i = blockIdx.y, d0 = blockIdx.x * 64;
    const int tid = threadIdx.x;
    #pragma unroll
    for (int it = 0; it < 9; ++it) {           // 36 r x 64 dc
        int e = it * 256 + tid;
        int r = e >> 6, dc = e & 63;
        t[dc][r] = f2bs(img[((size_t)i * R_N + r) * D_N + d0 + dc]);
    }
    #pragma unroll
    for (int it = 0; it < 3; ++it) {           // zero r 36..47
        int e = it * 256 + tid;
        t[e & 63][36 + (e >> 6)] = 0;
    }
    __syncthreads();
    #pragma unroll
    for (int it = 0; it < 6; ++it) {           // 64 rows x 24 dwords, contiguous
        int e = it * 256 + tid;
        int dc = e / 24, wd = e - dc * 24;
        unsigned v = (unsigned)t[dc][2 * wd] | ((unsigned)t[dc][2 * wd + 1] << 16);
        ((unsigned*)imt)[(size_t)(i * D_N + d0 + dc) * 24 + wd] = v;
    }
}

// ---------------- A: TWO waves per (c,i), split on GEMM2's d dimension.
// Round-2 structure, round-2 bug fixed: __launch_bounds__(512,4) — NOT (512,8),
// which forced VGPR=32 and spilled the accumulators (FETCH 443MB, 550us).
// Each wave: full GEMM1 + softmax (duplicated per d-half, keeps waves
// independent), then GEMM2 over its 512-d half; wc l2norm completed by one
// cross-wave LDS exchange + single __syncthreads.
// Block = 8 waves = 4 captions x 2 d-halves sharing image i. Grid 1024 blocks;
// XCD decode -> 16-image x 32-caption tile per XCD (proven FETCH ~38MB).
// Occupancy: LDS 27KB -> 5 blocks/CU; grid gives 4/CU = 32 waves/CU (2x round 1).
__global__ __launch_bounds__(512, 4)
void k_pre(const unsigned short* __restrict__ img_b,
           const unsigned short* __restrict__ cap_b,
           const unsigned short* __restrict__ img_t,
           unsigned short* __restrict__ simg) {
    __shared__ __align__(16) unsigned short s_p[8][L_N * P_LD];   // 25600 B
    __shared__ float s_ss[4][2][48];                              // 1536 B

    const int n = blockIdx.y * 16 + blockIdx.x;      // linear id; XCD = n & 7
    const int x8 = n & 7, m = n >> 3;
    const int i    = ((x8 & 3) << 4) | (m >> 3);     // 16 images per XCD
    const int quad = ((x8 >> 2) << 3) | (m & 7);     // 8 c-quads (32 c) per XCD
    const int wave = threadIdx.x >> 6, lane = threadIdx.x & 63;
    const int cq = wave >> 1, dh = wave & 1;
    const int c = quad * 4 + cq;
    const int pair = c * I_N + i;
    const int q = lane >> 4, ln16 = lane & 15;

    const unsigned short* ai = img_b + i * (R_N * D_N);          // GEMM1 A (m=r)
    const unsigned short* bc = cap_b + c * (L_N * D_N);          // GEMM1 B (n=l), sim cap
    const unsigned short* imtc = img_t + (size_t)i * D_N * 48;   // GEMM2 A (m=d,k=r)
    unsigned short* sp = &s_p[wave][0];

    // zero own p slot (covers k-pad cols 36..39)
    for (int k = lane; k < L_N * P_LD / 2; k += 64) ((unsigned*)sp)[k] = 0;

    // ---- GEMM1: attn[r][l], full K=1024 in this wave ----
    f4 acc[3][3] = {};
    #pragma unroll 4
    for (int ks = 0; ks < 32; ++ks) {
        const int kb = ks * 32 + q * 8;
        s16x8 af[3], bf[3];
        af[0] = *(const s16x8*)(ai + ln16 * D_N + kb);
        af[1] = *(const s16x8*)(ai + (16 + ln16) * D_N + kb);
        af[2] = (ln16 < 4) ? *(const s16x8*)(ai + (32 + ln16) * D_N + kb) : (s16x8)0;
        bf[0] = *(const s16x8*)(bc + ln16 * D_N + kb);
        bf[1] = *(const s16x8*)(bc + (16 + ln16) * D_N + kb);
        bf[2] = (ln16 < 8) ? *(const s16x8*)(bc + (32 + ln16) * D_N + kb) : (s16x8)0;
        #pragma unroll
        for (int mt = 0; mt < 3; ++mt)
            #pragma unroll
            for (int nt = 0; nt < 3; ++nt)
                acc[mt][nt] = __builtin_amdgcn_mfma_f32_16x16x32_bf16(af[mt], bf[nt], acc[mt][nt], 0, 0, 0);
    }

    // ---- leaky relu ----
    #pragma unroll
    for (int mt = 0; mt < 3; ++mt)
        #pragma unroll
        for (int nt = 0; nt < 3; ++nt)
            #pragma unroll
            for (int j = 0; j < 4; ++j) {
                float v = acc[mt][nt][j];
                acc[mt][nt][j] = (v > 0.f) ? v : 0.1f * v;
            }
    // ---- l2norm over words l per region row r ----
    #pragma unroll
    for (int mt = 0; mt < 3; ++mt)
        #pragma unroll
        for (int j = 0; j < 4; ++j) {
            float ss = 0.f;
            #pragma unroll
            for (int nt = 0; nt < 3; ++nt) ss += acc[mt][nt][j] * acc[mt][nt][j];
            #pragma unroll
            for (int o = 1; o < 16; o <<= 1) ss += __shfl_xor(ss, o, 64);
            float inv = 1.f / (sqrtf(ss) + 1e-8f);
            #pragma unroll
            for (int nt = 0; nt < 3; ++nt) acc[mt][nt][j] *= inv;
        }
    // ---- softmax over regions r per word l; store p[l][r] to LDS ----
    #pragma unroll
    for (int nt = 0; nt < 3; ++nt) {
        const int l = nt * 16 + ln16;
        float mx = -1e30f;
        #pragma unroll
        for (int mt = 0; mt < 3; ++mt)
            #pragma unroll
            for (int j = 0; j < 4; ++j) {
                int r = mt * 16 + q * 4 + j;
                if (r < R_N) mx = fmaxf(mx, 9.f * acc[mt][nt][j]);
            }
        mx = fmaxf(mx, __shfl_xor(mx, 16, 64));
        mx = fmaxf(mx, __shfl_xor(mx, 32, 64));
        float sum = 0.f;
        #pragma unroll
        for (int mt = 0; mt < 3; ++mt)
            #pragma unroll
            for (int j = 0; j < 4; ++j) {
                int r = mt * 16 + q * 4 + j;
                float e = (r < R_N) ? __expf(9.f * acc[mt][nt][j] - mx) : 0.f;
                acc[mt][nt][j] = e;
                sum += e;
            }
        sum += __shfl_xor(sum, 16, 64);
        sum += __shfl_xor(sum, 32, 64);
        float inv = 1.f / sum;
        #pragma unroll
        for (int mt = 0; mt < 3; ++mt)
            #pragma unroll
            for (int j = 0; j < 4; ++j) {
                int r = mt * 16 + q * 4 + j;
                if (r < R_N && l < L_N) sp[l * P_LD + r] = f2bs(acc[mt][nt][j] * inv);
            }
    }
    // same-wave DS ordering: reads below see the writes (no barrier needed).

    // ---- GEMM2 p-fragments (B operand [n=l][k=r]); predicated for 40x40 slot ----
    s16x8 paf[3][2];
    #pragma unroll
    for (int nl = 0; nl < 3; ++nl)
        #pragma unroll
        for (int ks = 0; ks < 2; ++ks) {
            const bool live = (nl < 2 || ln16 < 8) && (ks == 0 || q == 0);
            paf[nl][ks] = live ? *(const s16x8*)(sp + (nl * 16 + ln16) * P_LD + ks * 32 + q * 8)
                               : (s16x8)0;
        }

    const int ch0 = dh * 16;   // this wave's d-half: chunks ch0..ch0+15 (512 d)

    // ---- GEMM2 pass 1: d-half sumsq (A=imt rows d, B=p rows l) ----
    // C layout: row (q*4+j) = d (4 consecutive per lane), col ln16 = l.
    float rs[3] = {};
    #pragma unroll 2
    for (int chh = 0; chh < 16; ++chh) {
        const int ch = ch0 + chh;
        f4 a2[2][3] = {};
        #pragma unroll
        for (int ks = 0; ks < 2; ++ks) {
            const int kb = ks * 32 + q * 8;
            #pragma unroll
            for (int md = 0; md < 2; ++md) {
                const int drow = ch * 32 + md * 16 + ln16;
                s16x8 afr = *(const s16x8*)(imtc + drow * 48 + kb);
                #pragma unroll
                for (int nl = 0; nl < 3; ++nl)
                    a2[md][nl] = __builtin_amdgcn_mfma_f32_16x16x32_bf16(afr, paf[nl][ks], a2[md][nl], 0, 0, 0);
            }
        }
        #pragma unroll
        for (int md = 0; md < 2; ++md)
            #pragma unroll
            for (int nl = 0; nl < 3; ++nl)
                #pragma unroll
                for (int j = 0; j < 4; ++j)
                    rs[nl] += a2[md][nl][j] * a2[md][nl][j];
    }
    float hs[3];
    #pragma unroll
    for (int nl = 0; nl < 3; ++nl) {
        float s = rs[nl];
        s += __shfl_xor(s, 16, 64);
        s += __shfl_xor(s, 32, 64);
        hs[nl] = s;
    }
    // cross-wave exchange with the partner d-half
    if (q == 0) {
        #pragma unroll
        for (int nl = 0; nl < 3; ++nl) s_ss[cq][dh][nl * 16 + ln16] = hs[nl];
    }
    __syncthreads();
    float inv2[3];
    #pragma unroll
    for (int nl = 0; nl < 3; ++nl) {
        float tot = hs[nl] + s_ss[cq][dh ^ 1][nl * 16 + ln16];
        inv2[nl] = 1.f / (sqrtf(tot) + 1e-8f);
    }

    // ---- GEMM2 pass 2: recompute wc (own d-half), sim=(wc*inv-cap)^2 -> global ----
    unsigned short* so = simg + (size_t)pair * L_N * D_N;
    #pragma unroll 2
    for (int chh = 0; chh < 16; ++chh) {
        const int ch = ch0 + chh;
        f4 a2[2][3] = {};
        #pragma unroll
        for (int ks = 0; ks < 2; ++ks) {
            const int kb = ks * 32 + q * 8;
            #pragma unroll
            for (int md = 0; md < 2; ++md) {
                const int drow = ch * 32 + md * 16 + ln16;
                s16x8 afr = *(const s16x8*)(imtc + drow * 48 + kb);
                #pragma unroll
                for (int nl = 0; nl < 3; ++nl)
                    a2[md][nl] = __builtin_amdgcn_mfma_f32_16x16x32_bf16(afr, paf[nl][ks], a2[md][nl], 0, 0, 0);
            }
        }
        #pragma unroll
        for (int nl = 0; nl < 3; ++nl) {
            const int l = nl * 16 + ln16;
            if (l < L_N) {
                const float iv = inv2[nl];
                #pragma unroll
                for (int md = 0; md < 2; ++md) {
                    const int db = ch * 32 + md * 16 + q * 4;   // 4 consecutive d
                    const s16x4 cv = *(const s16x4*)(bc + l * D_N + db);
                    s16x4 ov;
                    #pragma unroll
                    for (int j = 0; j < 4; ++j) {
                        float dv = a2[md][nl][j] * iv - bs2f((unsigned short)cv[j]);
                        ov[j] = (short)f2bs(dv * dv);
                    }
                    __builtin_nontemporal_store(ov, (s16x4*)(so + l * D_N + db));
                }
            }
        }
    }
}

// ---------------- B: GEMM3  out = l2norm(relu(sim @ W + b)) * mask ----------------
// M=163840, K=1024, N=256. Tile 128x256, BK=64, 8 waves (2 M-groups x 4 N-groups).
// Proven round-0/1 version (do not re-pipeline: __syncthreads drains vmcnt, the
// round-3 BK=32 dbuf variant was ~35us slower).
__global__ __launch_bounds__(512, 4)
void k_gemm3(const unsigned short* __restrict__ simg,
             const unsigned short* __restrict__ wt,
             const int* __restrict__ cap_lens,
             const float* __restrict__ bias,
             float* __restrict__ out) {
    __shared__ __align__(16) unsigned short sA[128 * 64];   // 16 KB, XOR-swizzled cols
    __shared__ __align__(16) unsigned short sB[256 * 64];   // 32 KB
    __shared__ float s_sum[128];

    const int tid = threadIdx.x;
    const int w = tid >> 6, lane = tid & 63;
    const int ln16 = lane & 15, q = lane >> 4;
    const int wm = (w >> 2) * 64, wn = (w & 3) * 64;
    const int m0 = blockIdx.x * 128;
    const int cgg = ((lane & 7) ^ (lane >> 3)) << 3;   // swizzled source col (shorts)
    const int lrow8 = lane >> 3;
    const int rx = ln16 & 7;

    if (tid < 128) s_sum[tid] = 0.f;

    f4 acc[4][4] = {};
    #pragma unroll 1
    for (int kc = 0; kc < 16; ++kc) {
        const int kofs = kc * 64;
        #pragma unroll
        for (int it = 0; it < 2; ++it) {
            int row = it * 64 + w * 8 + lrow8;
            async16(simg + (size_t)(m0 + row) * D_N + kofs + cgg,
                    sA + (it * 512 + w * 64) * 8);
        }
        #pragma unroll
        for (int it = 0; it < 4; ++it) {
            int row = it * 64 + w * 8 + lrow8;
            async16(wt + (size_t)row * D_N + kofs + cgg,
                    sB + (it * 512 + w * 64) * 8);
        }
        __syncthreads();
        #pragma unroll
        for (int ks = 0; ks < 2; ++ks) {
            const int g = ks * 4 + q;
            s16x8 af[4], bf[4];
            #pragma unroll
            for (int mt = 0; mt < 4; ++mt) {
                int row = wm + mt * 16 + ln16;
                af[mt] = *(const s16x8*)(sA + row * 64 + ((g ^ rx) << 3));
            }
            #pragma unroll
            for (int nt = 0; nt < 4; ++nt) {
                int row = wn + nt * 16 + ln16;
                bf[nt] = *(const s16x8*)(sB + row * 64 + ((g ^ rx) << 3));
            }
            #pragma unroll
            for (int mt = 0; mt < 4; ++mt)
                #pragma unroll
                for (int nt = 0; nt < 4; ++nt)
                    acc[mt][nt] = __builtin_amdgcn_mfma_f32_16x16x32_bf16(af[mt], bf[nt], acc[mt][nt], 0, 0, 0);
        }
        __syncthreads();
    }

    // epilogue: +bias, relu, sumsq over s (cross-wave LDS), l2norm, mask, store
    float bv[4];
    #pragma unroll
    for (int nt = 0; nt < 4; ++nt) bv[nt] = bias[wn + nt * 16 + ln16];
    #pragma unroll
    for (int mt = 0; mt < 4; ++mt)
        #pragma unroll
        for (int j = 0; j < 4; ++j) {
            float s = 0.f;
            #pragma unroll
            for (int nt = 0; nt < 4; ++nt) {
                float v = acc[mt][nt][j] + bv[nt];
                v = fmaxf(v, 0.f);
                acc[mt][nt][j] = v;
                s += v * v;
            }
            #pragma unroll
            for (int o = 1; o < 16; o <<= 1) s += __shfl_xor(s, o, 64);
            if (ln16 == 0) atomicAdd(&s_sum[wm + mt * 16 + q * 4 + j], s);
        }
    __syncthreads();
    if (tid < 128) {
        int grow = m0 + tid;
        int c = grow / (I_N * L_N);
        int l = grow % L_N;
        float inv = 1.f / (sqrtf(s_sum[tid]) + 1e-8f);
        s_sum[tid] = (l < cap_lens[c]) ? inv : 0.f;
    }
    __syncthreads();
    #pragma unroll
    for (int mt = 0; mt < 4; ++mt)
        #pragma unroll
        for (int j = 0; j < 4; ++j) {
            const int rt = wm + mt * 16 + q * 4 + j;
            const float sc = s_sum[rt];
            #pragma unroll
            for (int nt = 0; nt < 4; ++nt)
                __builtin_nontemporal_store(acc[mt][nt][j] * sc,
                    &out[(size_t)(m0 + rt) * S_N + wn + nt * 16 + ln16]);
        }
}

extern "C" void kernel_launch(void* const* d_in, const int* in_sizes, int n_in,
                              void* d_out, int out_size, void* d_ws, size_t ws_size,
                              hipStream_t stream) {
    const float* img  = (const float*)d_in[0];
    const float* cap  = (const float*)d_in[1];
    const int*   lens = (const int*)d_in[2];
    const float* W    = (const float*)d_in[5];
    const float* bias = (const float*)d_in[6];
    float* out = (float*)d_out;
    unsigned short* ws = (unsigned short*)d_ws;

    k_convert<<<10240, 256, 0, stream>>>(img, cap, W, ws);
    dim3 gridT(16, I_N);
    k_imt<<<gridT, 256, 0, stream>>>(img, ws + OFF_IMT);

    dim3 gridP(16, I_N);  // 1024 blocks; kernel decodes (quad,i) with XCD-tile remap
    k_pre<<<gridP, 512, 0, stream>>>(ws, ws + OFF_CAP, ws + OFF_IMT, ws + OFF_SIM);

    k_gemm3<<<M_ALL / 128, 512, 0, stream>>>(ws + OFF_SIM, ws + OFF_WT, lens, bias, out);
}

// Round 6
// 629.431 us; speedup vs baseline: 1.7534x; 1.0223x over previous
//
#include <hip/hip_runtime.h>

#define C_N 64
#define I_N 64
#define R_N 36
#define L_N 40
#define D_N 1024
#define S_N 256

#define P_LD 72   // p row stride (shorts): 144 B, 16B-aligned rows

// ws layout (shorts):
#define OFF_CAP 2359296               // img end
#define OFF_WT  4980736               // cap end: Wt [s][d]
#define OFF_IMT 5242880               // wt end: img_t [i][d][r48]
#define OFF_SLK 8388608               // TRUE imt end: 64 zero shorts (k-overread slack)
#define OFF_SIM 8388672               // sim [pair*40 + l][1024] bf16
#define M_ALL   (C_N * I_N * L_N)

typedef float f4 __attribute__((ext_vector_type(4)));
typedef short s16x8 __attribute__((ext_vector_type(8)));
typedef short s16x4 __attribute__((ext_vector_type(4)));

__device__ __forceinline__ unsigned short f2bs(float f) {
    union { float f; unsigned u; } v; v.f = f;
    unsigned r = v.u + 0x7FFFu + ((v.u >> 16) & 1u);
    return (unsigned short)(r >> 16);
}
__device__ __forceinline__ float bs2f(unsigned short s) {
    union { unsigned u; float f; } v; v.u = ((unsigned)s) << 16;
    return v.f;
}
__device__ __forceinline__ void async16(const unsigned short* g, unsigned short* l) {
    __builtin_amdgcn_global_load_lds(
        (const __attribute__((address_space(1))) unsigned int*)g,
        (__attribute__((address_space(3))) unsigned int*)l, 16, 0, 0);
}

// ---------------- K0: linear converts ----------------
__global__ void k_convert(const float* __restrict__ img, const float* __restrict__ cap,
                          const float* __restrict__ W, unsigned short* __restrict__ ws) {
    int t = blockIdx.x * 256 + threadIdx.x;
    if (t < I_N * R_N * D_N) ws[t] = f2bs(img[t]);
    if (t < C_N * L_N * D_N) ws[OFF_CAP + t] = f2bs(cap[t]);
    if (t < D_N * S_N) {                       // W[d][s] -> Wt[s][d]
        int d = t >> 8, s = t & 255;
        ws[OFF_WT + s * D_N + d] = f2bs(W[t]);
    }
    if (t < 64) ws[OFF_SLK + t] = 0;
}

// ---------------- K0b: img [i][r][d] f32 -> imt [i][d][r48] bf16, LDS-tiled ----------
__global__ __launch_bounds__(256)
void k_imt(const float* __restrict__ img, unsigned short* __restrict__ imt) {
    __shared__ unsigned short t[64][50];
    const int i = blockIdx.y, d0 = blockIdx.x * 64;
    const int tid = threadIdx.x;
    #pragma unroll
    for (int it = 0; it < 9; ++it) {           // 36 r x 64 dc
        int e = it * 256 + tid;
        int r = e >> 6, dc = e & 63;
        t[dc][r] = f2bs(img[((size_t)i * R_N + r) * D_N + d0 + dc]);
    }
    #pragma unroll
    for (int it = 0; it < 3; ++it) {           // zero r 36..47
        int e = it * 256 + tid;
        t[e & 63][36 + (e >> 6)] = 0;
    }
    __syncthreads();
    #pragma unroll
    for (int it = 0; it < 6; ++it) {           // 64 rows x 24 dwords, contiguous
        int e = it * 256 + tid;
        int dc = e / 24, wd = e - dc * 24;
        unsigned v = (unsigned)t[dc][2 * wd] | ((unsigned)t[dc][2 * wd + 1] << 16);
        ((unsigned*)imt)[(size_t)(i * D_N + d0 + dc) * 24 + wd] = v;
    }
}

// ---------------- A: one WAVE per (c,i) — ROUND-1 PROVEN VERSION (295us).
// Round-5 lesson: d-split (2 waves/pair) raised occupancy 35->40% only and
// regressed to 337us (+27% MFMA, +43% loads); bound is per-wave load pipeline,
// not wave count. Keep this structure.
__global__ __launch_bounds__(512, 4)
void k_pre(const unsigned short* __restrict__ img_b,
           const unsigned short* __restrict__ cap_b,
           const unsigned short* __restrict__ img_t,
           unsigned short* __restrict__ simg) {
    __shared__ __align__(16) unsigned short s_p[8][48 * P_LD];   // 55296 B

    const int n = blockIdx.y * 8 + blockIdx.x;       // linear id; XCD = n & 7
    const int x = n & 7, m = n >> 3;
    const int i   = ((x & 3) << 4) | (m >> 2);       // 16 images per XCD
    const int oct = ((x >> 2) << 2) | (m & 3);       // 4 octets per XCD
    const int wave = threadIdx.x >> 6, lane = threadIdx.x & 63;
    const int c = oct * 8 + wave;
    const int pair = c * I_N + i;
    const int q = lane >> 4, ln16 = lane & 15;

    const unsigned short* ai = img_b + i * (R_N * D_N);          // GEMM1 A (m=r)
    const unsigned short* bc = cap_b + c * (L_N * D_N);          // GEMM1 B (n=l), sim cap
    const unsigned short* imtc = img_t + (size_t)i * D_N * 48;   // GEMM2 A (m=d,k=r)
    unsigned short* sp = &s_p[wave][0];

    // zero own p slot (covers m-pad rows 40..47 and k-pad cols 36..71)
    for (int k = lane; k < 48 * P_LD / 2; k += 64) ((unsigned*)sp)[k] = 0;

    // ---- GEMM1: attn[r][l], full K=1024 in this wave ----
    f4 acc[3][3] = {};
    #pragma unroll 4
    for (int ks = 0; ks < 32; ++ks) {
        const int kb = ks * 32 + q * 8;
        s16x8 af[3], bf[3];
        af[0] = *(const s16x8*)(ai + ln16 * D_N + kb);
        af[1] = *(const s16x8*)(ai + (16 + ln16) * D_N + kb);
        af[2] = (ln16 < 4) ? *(const s16x8*)(ai + (32 + ln16) * D_N + kb) : (s16x8)0;
        bf[0] = *(const s16x8*)(bc + ln16 * D_N + kb);
        bf[1] = *(const s16x8*)(bc + (16 + ln16) * D_N + kb);
        bf[2] = (ln16 < 8) ? *(const s16x8*)(bc + (32 + ln16) * D_N + kb) : (s16x8)0;
        #pragma unroll
        for (int mt = 0; mt < 3; ++mt)
            #pragma unroll
            for (int nt = 0; nt < 3; ++nt)
                acc[mt][nt] = __builtin_amdgcn_mfma_f32_16x16x32_bf16(af[mt], bf[nt], acc[mt][nt], 0, 0, 0);
    }

    // ---- leaky relu ----
    #pragma unroll
    for (int mt = 0; mt < 3; ++mt)
        #pragma unroll
        for (int nt = 0; nt < 3; ++nt)
            #pragma unroll
            for (int j = 0; j < 4; ++j) {
                float v = acc[mt][nt][j];
                acc[mt][nt][j] = (v > 0.f) ? v : 0.1f * v;
            }
    // ---- l2norm over words l per region row r ----
    #pragma unroll
    for (int mt = 0; mt < 3; ++mt)
        #pragma unroll
        for (int j = 0; j < 4; ++j) {
            float ss = 0.f;
            #pragma unroll
            for (int nt = 0; nt < 3; ++nt) ss += acc[mt][nt][j] * acc[mt][nt][j];
            #pragma unroll
            for (int o = 1; o < 16; o <<= 1) ss += __shfl_xor(ss, o, 64);
            float inv = 1.f / (sqrtf(ss) + 1e-8f);
            #pragma unroll
            for (int nt = 0; nt < 3; ++nt) acc[mt][nt][j] *= inv;
        }
    // ---- softmax over regions r per word l; store p[l][r] to LDS ----
    #pragma unroll
    for (int nt = 0; nt < 3; ++nt) {
        const int l = nt * 16 + ln16;
        float mx = -1e30f;
        #pragma unroll
        for (int mt = 0; mt < 3; ++mt)
            #pragma unroll
            for (int j = 0; j < 4; ++j) {
                int r = mt * 16 + q * 4 + j;
                if (r < R_N) mx = fmaxf(mx, 9.f * acc[mt][nt][j]);
            }
        mx = fmaxf(mx, __shfl_xor(mx, 16, 64));
        mx = fmaxf(mx, __shfl_xor(mx, 32, 64));
        float sum = 0.f;
        #pragma unroll
        for (int mt = 0; mt < 3; ++mt)
            #pragma unroll
            for (int j = 0; j < 4; ++j) {
                int r = mt * 16 + q * 4 + j;
                float e = (r < R_N) ? __expf(9.f * acc[mt][nt][j] - mx) : 0.f;
                acc[mt][nt][j] = e;
                sum += e;
            }
        sum += __shfl_xor(sum, 16, 64);
        sum += __shfl_xor(sum, 32, 64);
        float inv = 1.f / sum;
        #pragma unroll
        for (int mt = 0; mt < 3; ++mt)
            #pragma unroll
            for (int j = 0; j < 4; ++j) {
                int r = mt * 16 + q * 4 + j;
                if (r < R_N && l < L_N) sp[l * P_LD + r] = f2bs(acc[mt][nt][j] * inv);
            }
    }
    // same-wave DS ordering: reads below see the writes (no barrier needed).

    // ---- GEMM2 p-fragments once: used as B operand [n=l][k=r] ----
    s16x8 paf[3][2];
    #pragma unroll
    for (int nl = 0; nl < 3; ++nl)
        #pragma unroll
        for (int ks = 0; ks < 2; ++ks)
            paf[nl][ks] = *(const s16x8*)(sp + (nl * 16 + ln16) * P_LD + ks * 32 + q * 8);

    // ---- GEMM2 pass 1 (A=imt rows d, B=p rows l): wc sumsq over d ----
    // C layout: row (q*4+j) = d (4 consecutive per lane), col ln16 = l.
    float rs[3] = {};
    #pragma unroll 2
    for (int ch = 0; ch < 32; ++ch) {
        f4 a2[2][3] = {};
        #pragma unroll
        for (int ks = 0; ks < 2; ++ks) {
            const int kb = ks * 32 + q * 8;
            #pragma unroll
            for (int md = 0; md < 2; ++md) {
                const int drow = ch * 32 + md * 16 + ln16;
                s16x8 afr = *(const s16x8*)(imtc + drow * 48 + kb);
                #pragma unroll
                for (int nl = 0; nl < 3; ++nl)
                    a2[md][nl] = __builtin_amdgcn_mfma_f32_16x16x32_bf16(afr, paf[nl][ks], a2[md][nl], 0, 0, 0);
            }
        }
        #pragma unroll
        for (int md = 0; md < 2; ++md)
            #pragma unroll
            for (int nl = 0; nl < 3; ++nl)
                #pragma unroll
                for (int j = 0; j < 4; ++j)
                    rs[nl] += a2[md][nl][j] * a2[md][nl][j];
    }
    float inv2[3];
    #pragma unroll
    for (int nl = 0; nl < 3; ++nl) {
        float s = rs[nl];
        s += __shfl_xor(s, 16, 64);
        s += __shfl_xor(s, 32, 64);
        inv2[nl] = 1.f / (sqrtf(s) + 1e-8f);
    }

    // ---- GEMM2 pass 2: recompute wc, sim=(wc*inv-cap)^2 -> global bf16 (8B nt stores) ----
    unsigned short* so = simg + (size_t)pair * L_N * D_N;
    #pragma unroll 2
    for (int ch = 0; ch < 32; ++ch) {
        f4 a2[2][3] = {};
        #pragma unroll
        for (int ks = 0; ks < 2; ++ks) {
            const int kb = ks * 32 + q * 8;
            #pragma unroll
            for (int md = 0; md < 2; ++md) {
                const int drow = ch * 32 + md * 16 + ln16;
                s16x8 afr = *(const s16x8*)(imtc + drow * 48 + kb);
                #pragma unroll
                for (int nl = 0; nl < 3; ++nl)
                    a2[md][nl] = __builtin_amdgcn_mfma_f32_16x16x32_bf16(afr, paf[nl][ks], a2[md][nl], 0, 0, 0);
            }
        }
        #pragma unroll
        for (int nl = 0; nl < 3; ++nl) {
            const int l = nl * 16 + ln16;
            if (l < L_N) {
                const float iv = inv2[nl];
                #pragma unroll
                for (int md = 0; md < 2; ++md) {
                    const int db = ch * 32 + md * 16 + q * 4;   // 4 consecutive d
                    const s16x4 cv = *(const s16x4*)(bc + l * D_N + db);
                    s16x4 ov;
                    #pragma unroll
                    for (int j = 0; j < 4; ++j) {
                        float dv = a2[md][nl][j] * iv - bs2f((unsigned short)cv[j]);
                        ov[j] = (short)f2bs(dv * dv);
                    }
                    __builtin_nontemporal_store(ov, (s16x4*)(so + l * D_N + db));
                }
            }
        }
    }
}

// ---------------- B: GEMM3  out = l2norm(relu(sim @ W + b)) * mask ----------------
// M=163840, K=1024, N=256. Tile 128x256, BK=32 double-buffered with COUNTED
// vmcnt + RAW s_barrier (T3/T4-minimum): next tile's 3 async16 stay in flight
// across the barrier; only current tile's are waited (vmcnt(3)). This removes
// the vmcnt(0) drain that __syncthreads imposed (round-3 failure mode).
__global__ __launch_bounds__(512, 4)
void k_gemm3(const unsigned short* __restrict__ simg,
             const unsigned short* __restrict__ wt,
             const int* __restrict__ cap_lens,
             const float* __restrict__ bias,
             float* __restrict__ out) {
    __shared__ __align__(16) unsigned short sA[2][128 * 32];   // 8 KB x2
    __shared__ __align__(16) unsigned short sB[2][256 * 32];   // 16 KB x2
    __shared__ float s_sum[128];

    const int tid = threadIdx.x;
    const int w = tid >> 6, lane = tid & 63;
    const int ln16 = lane & 15, q = lane >> 4;
    const int wm = (w >> 2) * 64, wn = (w & 3) * 64;
    const int m0 = blockIdx.x * 128;
    // staging: row = tid>>2 (128 rows), slot = tid&3; source col-chunk = slot^(row&3)
    const int srow = tid >> 2;
    const int sw_a = ((tid & 3) ^ (srow & 3)) << 3;     // shorts
    const int srow2 = 128 + srow;
    const int sw_b2 = ((tid & 3) ^ (srow2 & 3)) << 3;
    const unsigned short* gA = simg + (size_t)(m0 + srow) * D_N + sw_a;
    const unsigned short* gB0 = wt + (size_t)srow * D_N + sw_a;
    const unsigned short* gB1 = wt + (size_t)srow2 * D_N + sw_b2;
    unsigned short* const lA = (unsigned short*)sA + w * 512;   // + buf*4096
    unsigned short* const lB = (unsigned short*)sB + w * 512;   // + buf*8192 (+4096 for B1)

    if (tid < 128) s_sum[tid] = 0.f;

    // prologue: stage tile 0 into buf 0 (3 loads/wave, left in flight)
    async16(gA, lA);
    async16(gB0, lB);
    async16(gB1, lB + 4096);

    f4 acc[4][4] = {};
    #pragma unroll 1
    for (int kc = 0; kc < 31; ++kc) {
        const int nb = (kc + 1) & 1;
        const int kofs = (kc + 1) * 32;
        async16(gA + kofs, lA + nb * 4096);              // next tile: 3 loads/wave
        async16(gB0 + kofs, lB + nb * 8192);
        async16(gB1 + kofs, lB + nb * 8192 + 4096);
        asm volatile("s_waitcnt vmcnt(3)" ::: "memory"); // current tile done; next in flight
        __builtin_amdgcn_s_barrier();                    // raw: no vmcnt drain
        __builtin_amdgcn_sched_barrier(0);
        const unsigned short* cA = (const unsigned short*)sA + (kc & 1) * 4096;
        const unsigned short* cB = (const unsigned short*)sB + (kc & 1) * 8192;
        s16x8 af[4], bf[4];
        #pragma unroll
        for (int mt = 0; mt < 4; ++mt) {
            int row = wm + mt * 16 + ln16;
            af[mt] = *(const s16x8*)(cA + row * 32 + ((q ^ (row & 3)) << 3));
        }
        #pragma unroll
        for (int nt = 0; nt < 4; ++nt) {
            int row = wn + nt * 16 + ln16;
            bf[nt] = *(const s16x8*)(cB + row * 32 + ((q ^ (row & 3)) << 3));
        }
        #pragma unroll
        for (int mt = 0; mt < 4; ++mt)
            #pragma unroll
            for (int nt = 0; nt < 4; ++nt)
                acc[mt][nt] = __builtin_amdgcn_mfma_f32_16x16x32_bf16(af[mt], bf[nt], acc[mt][nt], 0, 0, 0);
        __builtin_amdgcn_s_barrier();                    // all reads of cur buf done
    }
    // epilogue tile 31 (buf 1): nothing left in flight after this wait
    asm volatile("s_waitcnt vmcnt(0)" ::: "memory");
    __builtin_amdgcn_s_barrier();
    __builtin_amdgcn_sched_barrier(0);
    {
        const unsigned short* cA = (const unsigned short*)sA + 4096;
        const unsigned short* cB = (const unsigned short*)sB + 8192;
        s16x8 af[4], bf[4];
        #pragma unroll
        for (int mt = 0; mt < 4; ++mt) {
            int row = wm + mt * 16 + ln16;
            af[mt] = *(const s16x8*)(cA + row * 32 + ((q ^ (row & 3)) << 3));
        }
        #pragma unroll
        for (int nt = 0; nt < 4; ++nt) {
            int row = wn + nt * 16 + ln16;
            bf[nt] = *(const s16x8*)(cB + row * 32 + ((q ^ (row & 3)) << 3));
        }
        #pragma unroll
        for (int mt = 0; mt < 4; ++mt)
            #pragma unroll
            for (int nt = 0; nt < 4; ++nt)
                acc[mt][nt] = __builtin_amdgcn_mfma_f32_16x16x32_bf16(af[mt], bf[nt], acc[mt][nt], 0, 0, 0);
    }

    // epilogue: +bias, relu, sumsq over s (cross-wave LDS), l2norm, mask, store
    float bv[4];
    #pragma unroll
    for (int nt = 0; nt < 4; ++nt) bv[nt] = bias[wn + nt * 16 + ln16];
    #pragma unroll
    for (int mt = 0; mt < 4; ++mt)
        #pragma unroll
        for (int j = 0; j < 4; ++j) {
            float s = 0.f;
            #pragma unroll
            for (int nt = 0; nt < 4; ++nt) {
                float v = acc[mt][nt][j] + bv[nt];
                v = fmaxf(v, 0.f);
                acc[mt][nt][j] = v;
                s += v * v;
            }
            #pragma unroll
            for (int o = 1; o < 16; o <<= 1) s += __shfl_xor(s, o, 64);
            if (ln16 == 0) atomicAdd(&s_sum[wm + mt * 16 + q * 4 + j], s);
        }
    __syncthreads();
    if (tid < 128) {
        int grow = m0 + tid;
        int c = grow / (I_N * L_N);
        int l = grow % L_N;
        float inv = 1.f / (sqrtf(s_sum[tid]) + 1e-8f);
        s_sum[tid] = (l < cap_lens[c]) ? inv : 0.f;
    }
    __syncthreads();
    #pragma unroll
    for (int mt = 0; mt < 4; ++mt)
        #pragma unroll
        for (int j = 0; j < 4; ++j) {
            const int rt = wm + mt * 16 + q * 4 + j;
            const float sc = s_sum[rt];
            #pragma unroll
            for (int nt = 0; nt < 4; ++nt)
                __builtin_nontemporal_store(acc[mt][nt][j] * sc,
                    &out[(size_t)(m0 + rt) * S_N + wn + nt * 16 + ln16]);
        }
}

extern "C" void kernel_launch(void* const* d_in, const int* in_sizes, int n_in,
                              void* d_out, int out_size, void* d_ws, size_t ws_size,
                              hipStream_t stream) {
    const float* img  = (const float*)d_in[0];
    const float* cap  = (const float*)d_in[1];
    const int*   lens = (const int*)d_in[2];
    const float* W    = (const float*)d_in[5];
    const float* bias = (const float*)d_in[6];
    float* out = (float*)d_out;
    unsigned short* ws = (unsigned short*)d_ws;

    k_convert<<<10240, 256, 0, stream>>>(img, cap, W, ws);
    dim3 gridT(16, I_N);
    k_imt<<<gridT, 256, 0, stream>>>(img, ws + OFF_IMT);

    dim3 gridP(8, I_N);   // 512 blocks; kernel decodes (oct,i) with XCD-tile remap
    k_pre<<<gridP, 512, 0, stream>>>(ws, ws + OFF_CAP, ws + OFF_IMT, ws + OFF_SIM);

    k_gemm3<<<M_ALL / 128, 512, 0, stream>>>(ws + OFF_SIM, ws + OFF_WT, lens, bias, out);
}

// Round 7
// 526.076 us; speedup vs baseline: 2.0979x; 1.1965x over previous
//
#include <hip/hip_runtime.h>

#define C_N 64
#define I_N 64
#define R_N 36
#define L_N 40
#define D_N 1024
#define S_N 256

#define P_LD 72   // p row stride (shorts): 144 B, 16B-aligned rows

// ws layout (shorts):
#define OFF_CAP 2359296               // img end
#define OFF_WT  4980736               // cap end: wt_t [ch:32][s:256][e:32] (K-major chunks)
#define OFF_IMT 5242880               // wt end: img_t [i][d][r48]
#define OFF_SLK 8388608               // imt end: 64 zero shorts (slack)
#define OFF_SIM 8388672               // sim_t [ch:32][m:163840][e:32] bf16 (K-major chunks)
#define M_ALL   (C_N * I_N * L_N)
#define CH_STRIDE ((size_t)M_ALL * 32)   // shorts per sim_t chunk plane

typedef float f4 __attribute__((ext_vector_type(4)));
typedef short s16x8 __attribute__((ext_vector_type(8)));
typedef short s16x4 __attribute__((ext_vector_type(4)));

__device__ __forceinline__ unsigned short f2bs(float f) {
    union { float f; unsigned u; } v; v.f = f;
    unsigned r = v.u + 0x7FFFu + ((v.u >> 16) & 1u);
    return (unsigned short)(r >> 16);
}
__device__ __forceinline__ float bs2f(unsigned short s) {
    union { unsigned u; float f; } v; v.u = ((unsigned)s) << 16;
    return v.f;
}
__device__ __forceinline__ void async16(const unsigned short* g, unsigned short* l) {
    __builtin_amdgcn_global_load_lds(
        (const __attribute__((address_space(1))) unsigned int*)g,
        (__attribute__((address_space(3))) unsigned int*)l, 16, 0, 0);
}

// ---------------- K0: linear converts ----------------
__global__ void k_convert(const float* __restrict__ img, const float* __restrict__ cap,
                          const float* __restrict__ W, unsigned short* __restrict__ ws) {
    int t = blockIdx.x * 256 + threadIdx.x;
    if (t < I_N * R_N * D_N) ws[t] = f2bs(img[t]);
    if (t < C_N * L_N * D_N) ws[OFF_CAP + t] = f2bs(cap[t]);
    if (t < D_N * S_N) {                       // W[d][s] -> wt_t[ch=d>>5][s][d&31]
        int d = t >> 8, s = t & 255;
        ws[OFF_WT + (((d >> 5) * 256 + s) * 32) + (d & 31)] = f2bs(W[t]);
    }
    if (t < 64) ws[OFF_SLK + t] = 0;
}

// ---------------- K0b: img [i][r][d] f32 -> imt [i][d][r48] bf16, LDS-tiled ----------
__global__ __launch_bounds__(256)
void k_imt(const float* __restrict__ img, unsigned short* __restrict__ imt) {
    __shared__ unsigned short t[64][50];
    const int i = blockIdx.y, d0 = blockIdx.x * 64;
    const int tid = threadIdx.x;
    #pragma unroll
    for (int it = 0; it < 9; ++it) {           // 36 r x 64 dc
        int e = it * 256 + tid;
        int r = e >> 6, dc = e & 63;
        t[dc][r] = f2bs(img[((size_t)i * R_N + r) * D_N + d0 + dc]);
    }
    #pragma unroll
    for (int it = 0; it < 3; ++it) {           // zero r 36..47
        int e = it * 256 + tid;
        t[e & 63][36 + (e >> 6)] = 0;
    }
    __syncthreads();
    #pragma unroll
    for (int it = 0; it < 6; ++it) {           // 64 rows x 24 dwords, contiguous
        int e = it * 256 + tid;
        int dc = e / 24, wd = e - dc * 24;
        unsigned v = (unsigned)t[dc][2 * wd] | ((unsigned)t[dc][2 * wd + 1] << 16);
        ((unsigned*)imt)[(size_t)(i * D_N + d0 + dc) * 24 + wd] = v;
    }
}

// ---------------- A: one WAVE per (c,i) — proven structure (294us), with sim
// stores RELAID to K-major chunks: per (pair,ch) one contiguous 2.5KB block
// (was 8B pieces at 64B-per-2KB-row stride -> DRAM page thrash).
__global__ __launch_bounds__(512, 4)
void k_pre(const unsigned short* __restrict__ img_b,
           const unsigned short* __restrict__ cap_b,
           const unsigned short* __restrict__ img_t,
           unsigned short* __restrict__ simg) {
    __shared__ __align__(16) unsigned short s_p[8][48 * P_LD];   // 55296 B

    const int n = blockIdx.y * 8 + blockIdx.x;       // linear id; XCD = n & 7
    const int x = n & 7, m = n >> 3;
    const int i   = ((x & 3) << 4) | (m >> 2);       // 16 images per XCD
    const int oct = ((x >> 2) << 2) | (m & 3);       // 4 octets per XCD
    const int wave = threadIdx.x >> 6, lane = threadIdx.x & 63;
    const int c = oct * 8 + wave;
    const int pair = c * I_N + i;
    const int q = lane >> 4, ln16 = lane & 15;

    const unsigned short* ai = img_b + i * (R_N * D_N);          // GEMM1 A (m=r)
    const unsigned short* bc = cap_b + c * (L_N * D_N);          // GEMM1 B (n=l), sim cap
    const unsigned short* imtc = img_t + (size_t)i * D_N * 48;   // GEMM2 A (m=d,k=r)
    unsigned short* sp = &s_p[wave][0];

    // zero own p slot (covers m-pad rows 40..47 and k-pad cols 36..71)
    for (int k = lane; k < 48 * P_LD / 2; k += 64) ((unsigned*)sp)[k] = 0;

    // ---- GEMM1: attn[r][l], full K=1024 in this wave ----
    f4 acc[3][3] = {};
    #pragma unroll 4
    for (int ks = 0; ks < 32; ++ks) {
        const int kb = ks * 32 + q * 8;
        s16x8 af[3], bf[3];
        af[0] = *(const s16x8*)(ai + ln16 * D_N + kb);
        af[1] = *(const s16x8*)(ai + (16 + ln16) * D_N + kb);
        af[2] = (ln16 < 4) ? *(const s16x8*)(ai + (32 + ln16) * D_N + kb) : (s16x8)0;
        bf[0] = *(const s16x8*)(bc + ln16 * D_N + kb);
        bf[1] = *(const s16x8*)(bc + (16 + ln16) * D_N + kb);
        bf[2] = (ln16 < 8) ? *(const s16x8*)(bc + (32 + ln16) * D_N + kb) : (s16x8)0;
        #pragma unroll
        for (int mt = 0; mt < 3; ++mt)
            #pragma unroll
            for (int nt = 0; nt < 3; ++nt)
                acc[mt][nt] = __builtin_amdgcn_mfma_f32_16x16x32_bf16(af[mt], bf[nt], acc[mt][nt], 0, 0, 0);
    }

    // ---- leaky relu ----
    #pragma unroll
    for (int mt = 0; mt < 3; ++mt)
        #pragma unroll
        for (int nt = 0; nt < 3; ++nt)
            #pragma unroll
            for (int j = 0; j < 4; ++j) {
                float v = acc[mt][nt][j];
                acc[mt][nt][j] = (v > 0.f) ? v : 0.1f * v;
            }
    // ---- l2norm over words l per region row r ----
    #pragma unroll
    for (int mt = 0; mt < 3; ++mt)
        #pragma unroll
        for (int j = 0; j < 4; ++j) {
            float ss = 0.f;
            #pragma unroll
            for (int nt = 0; nt < 3; ++nt) ss += acc[mt][nt][j] * acc[mt][nt][j];
            #pragma unroll
            for (int o = 1; o < 16; o <<= 1) ss += __shfl_xor(ss, o, 64);
            float inv = 1.f / (sqrtf(ss) + 1e-8f);
            #pragma unroll
            for (int nt = 0; nt < 3; ++nt) acc[mt][nt][j] *= inv;
        }
    // ---- softmax over regions r per word l; store p[l][r] to LDS ----
    #pragma unroll
    for (int nt = 0; nt < 3; ++nt) {
        const int l = nt * 16 + ln16;
        float mx = -1e30f;
        #pragma unroll
        for (int mt = 0; mt < 3; ++mt)
            #pragma unroll
            for (int j = 0; j < 4; ++j) {
                int r = mt * 16 + q * 4 + j;
                if (r < R_N) mx = fmaxf(mx, 9.f * acc[mt][nt][j]);
            }
        mx = fmaxf(mx, __shfl_xor(mx, 16, 64));
        mx = fmaxf(mx, __shfl_xor(mx, 32, 64));
        float sum = 0.f;
        #pragma unroll
        for (int mt = 0; mt < 3; ++mt)
            #pragma unroll
            for (int j = 0; j < 4; ++j) {
                int r = mt * 16 + q * 4 + j;
                float e = (r < R_N) ? __expf(9.f * acc[mt][nt][j] - mx) : 0.f;
                acc[mt][nt][j] = e;
                sum += e;
            }
        sum += __shfl_xor(sum, 16, 64);
        sum += __shfl_xor(sum, 32, 64);
        float inv = 1.f / sum;
        #pragma unroll
        for (int mt = 0; mt < 3; ++mt)
            #pragma unroll
            for (int j = 0; j < 4; ++j) {
                int r = mt * 16 + q * 4 + j;
                if (r < R_N && l < L_N) sp[l * P_LD + r] = f2bs(acc[mt][nt][j] * inv);
            }
    }
    // same-wave DS ordering: reads below see the writes (no barrier needed).

    // ---- GEMM2 p-fragments once: used as B operand [n=l][k=r] ----
    s16x8 paf[3][2];
    #pragma unroll
    for (int nl = 0; nl < 3; ++nl)
        #pragma unroll
        for (int ks = 0; ks < 2; ++ks)
            paf[nl][ks] = *(const s16x8*)(sp + (nl * 16 + ln16) * P_LD + ks * 32 + q * 8);

    // ---- GEMM2 pass 1 (A=imt rows d, B=p rows l): wc sumsq over d ----
    float rs[3] = {};
    #pragma unroll 2
    for (int ch = 0; ch < 32; ++ch) {
        f4 a2[2][3] = {};
        #pragma unroll
        for (int ks = 0; ks < 2; ++ks) {
            const int kb = ks * 32 + q * 8;
            #pragma unroll
            for (int md = 0; md < 2; ++md) {
                const int drow = ch * 32 + md * 16 + ln16;
                s16x8 afr = *(const s16x8*)(imtc + drow * 48 + kb);
                #pragma unroll
                for (int nl = 0; nl < 3; ++nl)
                    a2[md][nl] = __builtin_amdgcn_mfma_f32_16x16x32_bf16(afr, paf[nl][ks], a2[md][nl], 0, 0, 0);
            }
        }
        #pragma unroll
        for (int md = 0; md < 2; ++md)
            #pragma unroll
            for (int nl = 0; nl < 3; ++nl)
                #pragma unroll
                for (int j = 0; j < 4; ++j)
                    rs[nl] += a2[md][nl][j] * a2[md][nl][j];
    }
    float inv2[3];
    #pragma unroll
    for (int nl = 0; nl < 3; ++nl) {
        float s = rs[nl];
        s += __shfl_xor(s, 16, 64);
        s += __shfl_xor(s, 32, 64);
        inv2[nl] = 1.f / (sqrtf(s) + 1e-8f);
    }

    // ---- GEMM2 pass 2: sim=(wc*inv-cap)^2 -> sim_t[ch][pair*40+l][32] (contiguous) ----
    #pragma unroll 2
    for (int ch = 0; ch < 32; ++ch) {
        f4 a2[2][3] = {};
        #pragma unroll
        for (int ks = 0; ks < 2; ++ks) {
            const int kb = ks * 32 + q * 8;
            #pragma unroll
            for (int md = 0; md < 2; ++md) {
                const int drow = ch * 32 + md * 16 + ln16;
                s16x8 afr = *(const s16x8*)(imtc + drow * 48 + kb);
                #pragma unroll
                for (int nl = 0; nl < 3; ++nl)
                    a2[md][nl] = __builtin_amdgcn_mfma_f32_16x16x32_bf16(afr, paf[nl][ks], a2[md][nl], 0, 0, 0);
            }
        }
        const size_t chbase = (size_t)ch * CH_STRIDE + (size_t)pair * L_N * 32;
        #pragma unroll
        for (int nl = 0; nl < 3; ++nl) {
            const int l = nl * 16 + ln16;
            if (l < L_N) {
                const float iv = inv2[nl];
                #pragma unroll
                for (int md = 0; md < 2; ++md) {
                    const int dd = md * 16 + q * 4;             // col within chunk
                    const int db = ch * 32 + dd;                // global d (cap read)
                    const s16x4 cv = *(const s16x4*)(bc + l * D_N + db);
                    s16x4 ov;
                    #pragma unroll
                    for (int j = 0; j < 4; ++j) {
                        float dv = a2[md][nl][j] * iv - bs2f((unsigned short)cv[j]);
                        ov[j] = (short)f2bs(dv * dv);
                    }
                    __builtin_nontemporal_store(ov,
                        (s16x4*)(simg + chbase + (size_t)l * 32 + dd));
                }
            }
        }
    }
}

// ---------------- B: GEMM3  out = l2norm(relu(sim @ W + b)) * mask ----------------
// K-major layouts: A-tile stage = ONE contiguous 8KB read per (block,tile);
// B-tile = 16KB contiguous. Counted-vmcnt dbuf schedule (round-6). Source-side
// XOR swizzle (chunk = slot ^ ((row>>1)&3)) -> ds_read_b128 2-way only (free).
__global__ __launch_bounds__(512, 4)
void k_gemm3(const unsigned short* __restrict__ simt,
             const unsigned short* __restrict__ wtt,
             const int* __restrict__ cap_lens,
             const float* __restrict__ bias,
             float* __restrict__ out) {
    __shared__ __align__(16) unsigned short sA[2][128 * 32];   // 8 KB x2
    __shared__ __align__(16) unsigned short sB[2][256 * 32];   // 16 KB x2
    __shared__ float s_sum[128];

    const int tid = threadIdx.x;
    const int w = tid >> 6, lane = tid & 63;
    const int ln16 = lane & 15, q = lane >> 4;
    const int wm = (w >> 2) * 64, wn = (w & 3) * 64;
    const int m0 = blockIdx.x * 128;
    // staging: thread -> (row = tid>>2, slot = tid&3); source chunk pre-swizzled
    const int srow = tid >> 2;
    const int swz = ((tid & 3) ^ ((srow >> 1) & 3)) << 3;      // shorts
    const unsigned short* gA  = simt + ((size_t)(m0 + srow)) * 32 + swz;  // + kc*CH_STRIDE
    const unsigned short* gB0 = wtt + (size_t)srow * 32 + swz;            // + kc*8192
    const unsigned short* gB1 = wtt + (size_t)(128 + srow) * 32 + swz;    // same swz: +128 preserves (row>>1)&3
    unsigned short* const lA = (unsigned short*)sA + tid * 8;             // + buf*4096
    unsigned short* const lB = (unsigned short*)sB + tid * 8;             // + buf*8192 (+4096 for B1)

    if (tid < 128) s_sum[tid] = 0.f;

    // prologue: stage tile 0 into buf 0 (3 loads/wave, left in flight)
    async16(gA, lA);
    async16(gB0, lB);
    async16(gB1, lB + 4096);

    f4 acc[4][4] = {};
    #pragma unroll 1
    for (int kc = 0; kc < 31; ++kc) {
        const int nb = (kc + 1) & 1;
        async16(gA + (size_t)(kc + 1) * CH_STRIDE, lA + nb * 4096);
        async16(gB0 + (kc + 1) * 8192, lB + nb * 8192);
        async16(gB1 + (kc + 1) * 8192, lB + nb * 8192 + 4096);
        asm volatile("s_waitcnt vmcnt(3)" ::: "memory"); // cur tile landed; next in flight
        __builtin_amdgcn_s_barrier();
        __builtin_amdgcn_sched_barrier(0);
        const unsigned short* cA = (const unsigned short*)sA + (kc & 1) * 4096;
        const unsigned short* cB = (const unsigned short*)sB + (kc & 1) * 8192;
        s16x8 af[4], bf[4];
        #pragma unroll
        for (int mt = 0; mt < 4; ++mt) {
            int row = wm + mt * 16 + ln16;
            af[mt] = *(const s16x8*)(cA + row * 32 + ((q ^ ((row >> 1) & 3)) << 3));
        }
        #pragma unroll
        for (int nt = 0; nt < 4; ++nt) {
            int row = wn + nt * 16 + ln16;
            bf[nt] = *(const s16x8*)(cB + row * 32 + ((q ^ ((row >> 1) & 3)) << 3));
        }
        #pragma unroll
        for (int mt = 0; mt < 4; ++mt)
            #pragma unroll
            for (int nt = 0; nt < 4; ++nt)
                acc[mt][nt] = __builtin_amdgcn_mfma_f32_16x16x32_bf16(af[mt], bf[nt], acc[mt][nt], 0, 0, 0);
        __builtin_amdgcn_s_barrier();                    // all reads of cur buf done
    }
    // epilogue tile 31 (buf 1)
    asm volatile("s_waitcnt vmcnt(0)" ::: "memory");
    __builtin_amdgcn_s_barrier();
    __builtin_amdgcn_sched_barrier(0);
    {
        const unsigned short* cA = (const unsigned short*)sA + 4096;
        const unsigned short* cB = (const unsigned short*)sB + 8192;
        s16x8 af[4], bf[4];
        #pragma unroll
        for (int mt = 0; mt < 4; ++mt) {
            int row = wm + mt * 16 + ln16;
            af[mt] = *(const s16x8*)(cA + row * 32 + ((q ^ ((row >> 1) & 3)) << 3));
        }
        #pragma unroll
        for (int nt = 0; nt < 4; ++nt) {
            int row = wn + nt * 16 + ln16;
            bf[nt] = *(const s16x8*)(cB + row * 32 + ((q ^ ((row >> 1) & 3)) << 3));
        }
        #pragma unroll
        for (int mt = 0; mt < 4; ++mt)
            #pragma unroll
            for (int nt = 0; nt < 4; ++nt)
                acc[mt][nt] = __builtin_amdgcn_mfma_f32_16x16x32_bf16(af[mt], bf[nt], acc[mt][nt], 0, 0, 0);
    }

    // epilogue: +bias, relu, sumsq over s (cross-wave LDS), l2norm, mask, store
    float bv[4];
    #pragma unroll
    for (int nt = 0; nt < 4; ++nt) bv[nt] = bias[wn + nt * 16 + ln16];
    #pragma unroll
    for (int mt = 0; mt < 4; ++mt)
        #pragma unroll
        for (int j = 0; j < 4; ++j) {
            float s = 0.f;
            #pragma unroll
            for (int nt = 0; nt < 4; ++nt) {
                float v = acc[mt][nt][j] + bv[nt];
                v = fmaxf(v, 0.f);
                acc[mt][nt][j] = v;
                s += v * v;
            }
            #pragma unroll
            for (int o = 1; o < 16; o <<= 1) s += __shfl_xor(s, o, 64);
            if (ln16 == 0) atomicAdd(&s_sum[wm + mt * 16 + q * 4 + j], s);
        }
    __syncthreads();
    if (tid < 128) {
        int grow = m0 + tid;
        int c = grow / (I_N * L_N);
        int l = grow % L_N;
        float inv = 1.f / (sqrtf(s_sum[tid]) + 1e-8f);
        s_sum[tid] = (l < cap_lens[c]) ? inv : 0.f;
    }
    __syncthreads();
    #pragma unroll
    for (int mt = 0; mt < 4; ++mt)
        #pragma unroll
        for (int j = 0; j < 4; ++j) {
            const int rt = wm + mt * 16 + q * 4 + j;
            const float sc = s_sum[rt];
            #pragma unroll
            for (int nt = 0; nt < 4; ++nt)
                __builtin_nontemporal_store(acc[mt][nt][j] * sc,
                    &out[(size_t)(m0 + rt) * S_N + wn + nt * 16 + ln16]);
        }
}

extern "C" void kernel_launch(void* const* d_in, const int* in_sizes, int n_in,
                              void* d_out, int out_size, void* d_ws, size_t ws_size,
                              hipStream_t stream) {
    const float* img  = (const float*)d_in[0];
    const float* cap  = (const float*)d_in[1];
    const int*   lens = (const int*)d_in[2];
    const float* W    = (const float*)d_in[5];
    const float* bias = (const float*)d_in[6];
    float* out = (float*)d_out;
    unsigned short* ws = (unsigned short*)d_ws;

    k_convert<<<10240, 256, 0, stream>>>(img, cap, W, ws);
    dim3 gridT(16, I_N);
    k_imt<<<gridT, 256, 0, stream>>>(img, ws + OFF_IMT);

    dim3 gridP(8, I_N);   // 512 blocks; kernel decodes (oct,i) with XCD-tile remap
    k_pre<<<gridP, 512, 0, stream>>>(ws, ws + OFF_CAP, ws + OFF_IMT, ws + OFF_SIM);

    k_gemm3<<<M_ALL / 128, 512, 0, stream>>>(ws + OFF_SIM, ws + OFF_WT, lens, bias, out);
}

// Round 8
// 521.498 us; speedup vs baseline: 2.1163x; 1.0088x over previous
//
#include <hip/hip_runtime.h>

#define C_N 64
#define I_N 64
#define R_N 36
#define L_N 40
#define D_N 1024
#define S_N 256

#define P_LD 72   // p row stride (shorts): 144 B, 16B-aligned rows

// ws layout (shorts):
#define OFF_CAP 2359296               // img end
#define OFF_WT  4980736               // cap end: wt_t [ch:32][s:256][e:32] (K-major chunks)
#define OFF_IMT 5242880               // wt end: img_t [i][d][r48]
#define OFF_SLK 8388608               // imt end: 64 zero shorts (slack)
#define OFF_SIM 8388672               // sim_t [ch:32][m:163840][e:32] bf16 (K-major chunks)
#define M_ALL   (C_N * I_N * L_N)
#define CH_STRIDE ((size_t)M_ALL * 32)   // shorts per sim_t chunk plane
#define OFF_G   (OFF_SIM + 32 * CH_STRIDE)  // gram G [i][48][64] bf16 (0.4 MB)

typedef float f4 __attribute__((ext_vector_type(4)));
typedef short s16x8 __attribute__((ext_vector_type(8)));
typedef short s16x4 __attribute__((ext_vector_type(4)));

__device__ __forceinline__ unsigned short f2bs(float f) {
    union { float f; unsigned u; } v; v.f = f;
    unsigned r = v.u + 0x7FFFu + ((v.u >> 16) & 1u);
    return (unsigned short)(r >> 16);
}
__device__ __forceinline__ float bs2f(unsigned short s) {
    union { unsigned u; float f; } v; v.u = ((unsigned)s) << 16;
    return v.f;
}
__device__ __forceinline__ void async16(const unsigned short* g, unsigned short* l) {
    __builtin_amdgcn_global_load_lds(
        (const __attribute__((address_space(1))) unsigned int*)g,
        (__attribute__((address_space(3))) unsigned int*)l, 16, 0, 0);
}

// ---------------- K0: linear converts ----------------
__global__ void k_convert(const float* __restrict__ img, const float* __restrict__ cap,
                          const float* __restrict__ W, unsigned short* __restrict__ ws) {
    int t = blockIdx.x * 256 + threadIdx.x;
    if (t < I_N * R_N * D_N) ws[t] = f2bs(img[t]);
    if (t < C_N * L_N * D_N) ws[OFF_CAP + t] = f2bs(cap[t]);
    if (t < D_N * S_N) {                       // W[d][s] -> wt_t[ch=d>>5][s][d&31]
        int d = t >> 8, s = t & 255;
        ws[OFF_WT + (((d >> 5) * 256 + s) * 32) + (d & 31)] = f2bs(W[t]);
    }
    if (t < 64) ws[OFF_SLK + t] = 0;
}

// ---------------- K0b: img [i][r][d] f32 -> imt [i][d][r48] bf16, LDS-tiled ----------
__global__ __launch_bounds__(256)
void k_imt(const float* __restrict__ img, unsigned short* __restrict__ imt) {
    __shared__ unsigned short t[64][50];
    const int i = blockIdx.y, d0 = blockIdx.x * 64;
    const int tid = threadIdx.x;
    #pragma unroll
    for (int it = 0; it < 9; ++it) {           // 36 r x 64 dc
        int e = it * 256 + tid;
        int r = e >> 6, dc = e & 63;
        t[dc][r] = f2bs(img[((size_t)i * R_N + r) * D_N + d0 + dc]);
    }
    #pragma unroll
    for (int it = 0; it < 3; ++it) {           // zero r 36..47
        int e = it * 256 + tid;
        t[e & 63][36 + (e >> 6)] = 0;
    }
    __syncthreads();
    #pragma unroll
    for (int it = 0; it < 6; ++it) {           // 64 rows x 24 dwords, contiguous
        int e = it * 256 + tid;
        int dc = e / 24, wd = e - dc * 24;
        unsigned v = (unsigned)t[dc][2 * wd] | ((unsigned)t[dc][2 * wd + 1] << 16);
        ((unsigned*)imt)[(size_t)(i * D_N + d0 + dc) * 24 + wd] = v;
    }
}

// ---------------- K0c: per-image Gram G = A.A^T (A = 36x1024 bf16 regions) -------
// One wave per image. G[i][48][64] bf16: rows/cols 36..47 zero (from zeroed A
// fragments), cols 48..63 explicitly zeroed. ||wc_l||^2 = p_l^T G p_l later.
__global__ __launch_bounds__(64)
void k_gram(const unsigned short* __restrict__ img_b, unsigned short* __restrict__ g) {
    const int i = blockIdx.x;
    const int lane = threadIdx.x;
    const int q = lane >> 4, ln16 = lane & 15;
    const unsigned short* ai = img_b + i * (R_N * D_N);
    unsigned short* gi = g + i * (48 * 64);
    // zero cols 48..63 of all 48 rows (disjoint from computed region)
    for (int e = lane; e < 48 * 8; e += 64) {        // 8 dwords per row
        int r = e >> 3, wd = e & 7;
        ((unsigned*)(gi + r * 64 + 48))[wd] = 0;
    }
    f4 c[3][3] = {};
    #pragma unroll 4
    for (int ks = 0; ks < 32; ++ks) {
        const int kb = ks * 32 + q * 8;
        s16x8 af[3];
        af[0] = *(const s16x8*)(ai + ln16 * D_N + kb);
        af[1] = *(const s16x8*)(ai + (16 + ln16) * D_N + kb);
        af[2] = (ln16 < 4) ? *(const s16x8*)(ai + (32 + ln16) * D_N + kb) : (s16x8)0;
        #pragma unroll
        for (int mt = 0; mt < 3; ++mt)
            #pragma unroll
            for (int nt = 0; nt < 3; ++nt)
                c[mt][nt] = __builtin_amdgcn_mfma_f32_16x16x32_bf16(af[mt], af[nt], c[mt][nt], 0, 0, 0);
    }
    // C layout: row r = mt*16+q*4+j, col r' = nt*16+ln16
    #pragma unroll
    for (int mt = 0; mt < 3; ++mt)
        #pragma unroll
        for (int nt = 0; nt < 3; ++nt)
            #pragma unroll
            for (int j = 0; j < 4; ++j)
                gi[(mt * 16 + q * 4 + j) * 64 + nt * 16 + ln16] = f2bs(c[mt][nt][j]);
}

// ---------------- A: one WAVE per (c,i). GEMM2 pass-1 replaced by the Gram
// quadform: rs[l] = p_l^T G p_l via 18 MFMA (T = G.P^T reusing paf) + 9 ds_read
// + ~40 VALU — removes 384 MFMA + 131 KB of imt loads per wave.
__global__ __launch_bounds__(512, 4)
void k_pre(const unsigned short* __restrict__ img_b,
           const unsigned short* __restrict__ cap_b,
           const unsigned short* __restrict__ img_t,
           const unsigned short* __restrict__ gram,
           unsigned short* __restrict__ simg) {
    __shared__ __align__(16) unsigned short s_p[8][48 * P_LD];   // 55296 B

    const int n = blockIdx.y * 8 + blockIdx.x;       // linear id; XCD = n & 7
    const int x = n & 7, m = n >> 3;
    const int i   = ((x & 3) << 4) | (m >> 2);       // 16 images per XCD
    const int oct = ((x >> 2) << 2) | (m & 3);       // 4 octets per XCD
    const int wave = threadIdx.x >> 6, lane = threadIdx.x & 63;
    const int c = oct * 8 + wave;
    const int pair = c * I_N + i;
    const int q = lane >> 4, ln16 = lane & 15;

    const unsigned short* ai = img_b + i * (R_N * D_N);          // GEMM1 A (m=r)
    const unsigned short* bc = cap_b + c * (L_N * D_N);          // GEMM1 B (n=l), sim cap
    const unsigned short* imtc = img_t + (size_t)i * D_N * 48;   // GEMM2 A (m=d,k=r)
    unsigned short* sp = &s_p[wave][0];

    // zero own p slot (covers m-pad rows 40..47 and k-pad cols 36..71)
    for (int k = lane; k < 48 * P_LD / 2; k += 64) ((unsigned*)sp)[k] = 0;

    // ---- GEMM1: attn[r][l], full K=1024 in this wave ----
    f4 acc[3][3] = {};
    #pragma unroll 4
    for (int ks = 0; ks < 32; ++ks) {
        const int kb = ks * 32 + q * 8;
        s16x8 af[3], bf[3];
        af[0] = *(const s16x8*)(ai + ln16 * D_N + kb);
        af[1] = *(const s16x8*)(ai + (16 + ln16) * D_N + kb);
        af[2] = (ln16 < 4) ? *(const s16x8*)(ai + (32 + ln16) * D_N + kb) : (s16x8)0;
        bf[0] = *(const s16x8*)(bc + ln16 * D_N + kb);
        bf[1] = *(const s16x8*)(bc + (16 + ln16) * D_N + kb);
        bf[2] = (ln16 < 8) ? *(const s16x8*)(bc + (32 + ln16) * D_N + kb) : (s16x8)0;
        #pragma unroll
        for (int mt = 0; mt < 3; ++mt)
            #pragma unroll
            for (int nt = 0; nt < 3; ++nt)
                acc[mt][nt] = __builtin_amdgcn_mfma_f32_16x16x32_bf16(af[mt], bf[nt], acc[mt][nt], 0, 0, 0);
    }

    // ---- leaky relu ----
    #pragma unroll
    for (int mt = 0; mt < 3; ++mt)
        #pragma unroll
        for (int nt = 0; nt < 3; ++nt)
            #pragma unroll
            for (int j = 0; j < 4; ++j) {
                float v = acc[mt][nt][j];
                acc[mt][nt][j] = (v > 0.f) ? v : 0.1f * v;
            }
    // ---- l2norm over words l per region row r ----
    #pragma unroll
    for (int mt = 0; mt < 3; ++mt)
        #pragma unroll
        for (int j = 0; j < 4; ++j) {
            float ss = 0.f;
            #pragma unroll
            for (int nt = 0; nt < 3; ++nt) ss += acc[mt][nt][j] * acc[mt][nt][j];
            #pragma unroll
            for (int o = 1; o < 16; o <<= 1) ss += __shfl_xor(ss, o, 64);
            float inv = 1.f / (sqrtf(ss) + 1e-8f);
            #pragma unroll
            for (int nt = 0; nt < 3; ++nt) acc[mt][nt][j] *= inv;
        }
    // ---- softmax over regions r per word l; store p[l][r] to LDS ----
    #pragma unroll
    for (int nt = 0; nt < 3; ++nt) {
        const int l = nt * 16 + ln16;
        float mx = -1e30f;
        #pragma unroll
        for (int mt = 0; mt < 3; ++mt)
            #pragma unroll
            for (int j = 0; j < 4; ++j) {
                int r = mt * 16 + q * 4 + j;
                if (r < R_N) mx = fmaxf(mx, 9.f * acc[mt][nt][j]);
            }
        mx = fmaxf(mx, __shfl_xor(mx, 16, 64));
        mx = fmaxf(mx, __shfl_xor(mx, 32, 64));
        float sum = 0.f;
        #pragma unroll
        for (int mt = 0; mt < 3; ++mt)
            #pragma unroll
            for (int j = 0; j < 4; ++j) {
                int r = mt * 16 + q * 4 + j;
                float e = (r < R_N) ? __expf(9.f * acc[mt][nt][j] - mx) : 0.f;
                acc[mt][nt][j] = e;
                sum += e;
            }
        sum += __shfl_xor(sum, 16, 64);
        sum += __shfl_xor(sum, 32, 64);
        float inv = 1.f / sum;
        #pragma unroll
        for (int mt = 0; mt < 3; ++mt)
            #pragma unroll
            for (int j = 0; j < 4; ++j) {
                int r = mt * 16 + q * 4 + j;
                if (r < R_N && l < L_N) sp[l * P_LD + r] = f2bs(acc[mt][nt][j] * inv);
            }
    }
    // same-wave DS ordering: reads below see the writes (no barrier needed).

    // ---- GEMM2 p-fragments once: used as B operand [n=l][k=r] ----
    s16x8 paf[3][2];
    #pragma unroll
    for (int nl = 0; nl < 3; ++nl)
        #pragma unroll
        for (int ks = 0; ks < 2; ++ks)
            paf[nl][ks] = *(const s16x8*)(sp + (nl * 16 + ln16) * P_LD + ks * 32 + q * 8);

    // ---- Gram quadform: rs[l] = p_l^T G p_l  (replaces GEMM2 pass 1) ----
    // T = G.P^T: C row = r' (q*4+j + mt*16), col = l (ln16 + nl*16).
    const unsigned short* gi = gram + i * (48 * 64);
    f4 T[3][3] = {};
    #pragma unroll
    for (int ks = 0; ks < 2; ++ks) {
        const int kb = ks * 32 + q * 8;
        s16x8 ga[3];
        #pragma unroll
        for (int mt = 0; mt < 3; ++mt)
            ga[mt] = *(const s16x8*)(gi + (mt * 16 + ln16) * 64 + kb);
        #pragma unroll
        for (int mt = 0; mt < 3; ++mt)
            #pragma unroll
            for (int nl = 0; nl < 3; ++nl)
                T[mt][nl] = __builtin_amdgcn_mfma_f32_16x16x32_bf16(ga[mt], paf[nl][ks], T[mt][nl], 0, 0, 0);
    }
    float inv2[3];
    #pragma unroll
    for (int nl = 0; nl < 3; ++nl) {
        const int l = nl * 16 + ln16;
        float rsl = 0.f;
        #pragma unroll
        for (int mt = 0; mt < 3; ++mt) {
            const s16x4 pv = *(const s16x4*)(sp + l * P_LD + mt * 16 + q * 4);
            #pragma unroll
            for (int j = 0; j < 4; ++j)
                rsl += bs2f((unsigned short)pv[j]) * T[mt][nl][j];
        }
        rsl += __shfl_xor(rsl, 16, 64);
        rsl += __shfl_xor(rsl, 32, 64);
        inv2[nl] = 1.f / (sqrtf(rsl) + 1e-8f);
    }

    // ---- GEMM2 (single pass): sim=(wc*inv-cap)^2 -> sim_t[ch][pair*40+l][32] ----
    #pragma unroll 2
    for (int ch = 0; ch < 32; ++ch) {
        f4 a2[2][3] = {};
        #pragma unroll
        for (int ks = 0; ks < 2; ++ks) {
            const int kb = ks * 32 + q * 8;
            #pragma unroll
            for (int md = 0; md < 2; ++md) {
                const int drow = ch * 32 + md * 16 + ln16;
                s16x8 afr = *(const s16x8*)(imtc + drow * 48 + kb);
                #pragma unroll
                for (int nl = 0; nl < 3; ++nl)
                    a2[md][nl] = __builtin_amdgcn_mfma_f32_16x16x32_bf16(afr, paf[nl][ks], a2[md][nl], 0, 0, 0);
            }
        }
        const size_t chbase = (size_t)ch * CH_STRIDE + (size_t)pair * L_N * 32;
        #pragma unroll
        for (int nl = 0; nl < 3; ++nl) {
            const int l = nl * 16 + ln16;
            if (l < L_N) {
                const float iv = inv2[nl];
                #pragma unroll
                for (int md = 0; md < 2; ++md) {
                    const int dd = md * 16 + q * 4;             // col within chunk
                    const int db = ch * 32 + dd;                // global d (cap read)
                    const s16x4 cv = *(const s16x4*)(bc + l * D_N + db);
                    s16x4 ov;
                    #pragma unroll
                    for (int j = 0; j < 4; ++j) {
                        float dv = a2[md][nl][j] * iv - bs2f((unsigned short)cv[j]);
                        ov[j] = (short)f2bs(dv * dv);
                    }
                    __builtin_nontemporal_store(ov,
                        (s16x4*)(simg + chbase + (size_t)l * 32 + dd));
                }
            }
        }
    }
}

// ---------------- B: GEMM3  out = l2norm(relu(sim @ W + b)) * mask ----------------
// K-major layouts: A-tile stage = ONE contiguous 8KB read per (block,tile);
// B-tile = 16KB contiguous. Counted-vmcnt dbuf schedule. Source-side XOR swizzle
// (chunk = slot ^ ((row>>1)&3)) -> ds_read_b128 2-way only (free).
__global__ __launch_bounds__(512, 4)
void k_gemm3(const unsigned short* __restrict__ simt,
             const unsigned short* __restrict__ wtt,
             const int* __restrict__ cap_lens,
             const float* __restrict__ bias,
             float* __restrict__ out) {
    __shared__ __align__(16) unsigned short sA[2][128 * 32];   // 8 KB x2
    __shared__ __align__(16) unsigned short sB[2][256 * 32];   // 16 KB x2
    __shared__ float s_sum[128];

    const int tid = threadIdx.x;
    const int w = tid >> 6, lane = tid & 63;
    const int ln16 = lane & 15, q = lane >> 4;
    const int wm = (w >> 2) * 64, wn = (w & 3) * 64;
    const int m0 = blockIdx.x * 128;
    // staging: thread -> (row = tid>>2, slot = tid&3); source chunk pre-swizzled
    const int srow = tid >> 2;
    const int swz = ((tid & 3) ^ ((srow >> 1) & 3)) << 3;      // shorts
    const unsigned short* gA  = simt + ((size_t)(m0 + srow)) * 32 + swz;  // + kc*CH_STRIDE
    const unsigned short* gB0 = wtt + (size_t)srow * 32 + swz;            // + kc*8192
    const unsigned short* gB1 = wtt + (size_t)(128 + srow) * 32 + swz;
    unsigned short* const lA = (unsigned short*)sA + tid * 8;             // + buf*4096
    unsigned short* const lB = (unsigned short*)sB + tid * 8;             // + buf*8192 (+4096 for B1)

    if (tid < 128) s_sum[tid] = 0.f;

    // prologue: stage tile 0 into buf 0 (3 loads/wave, left in flight)
    async16(gA, lA);
    async16(gB0, lB);
    async16(gB1, lB + 4096);

    f4 acc[4][4] = {};
    #pragma unroll 1
    for (int kc = 0; kc < 31; ++kc) {
        const int nb = (kc + 1) & 1;
        async16(gA + (size_t)(kc + 1) * CH_STRIDE, lA + nb * 4096);
        async16(gB0 + (kc + 1) * 8192, lB + nb * 8192);
        async16(gB1 + (kc + 1) * 8192, lB + nb * 8192 + 4096);
        asm volatile("s_waitcnt vmcnt(3)" ::: "memory"); // cur tile landed; next in flight
        __builtin_amdgcn_s_barrier();
        __builtin_amdgcn_sched_barrier(0);
        const unsigned short* cA = (const unsigned short*)sA + (kc & 1) * 4096;
        const unsigned short* cB = (const unsigned short*)sB + (kc & 1) * 8192;
        s16x8 af[4], bf[4];
        #pragma unroll
        for (int mt = 0; mt < 4; ++mt) {
            int row = wm + mt * 16 + ln16;
            af[mt] = *(const s16x8*)(cA + row * 32 + ((q ^ ((row >> 1) & 3)) << 3));
        }
        #pragma unroll
        for (int nt = 0; nt < 4; ++nt) {
            int row = wn + nt * 16 + ln16;
            bf[nt] = *(const s16x8*)(cB + row * 32 + ((q ^ ((row >> 1) & 3)) << 3));
        }
        #pragma unroll
        for (int mt = 0; mt < 4; ++mt)
            #pragma unroll
            for (int nt = 0; nt < 4; ++nt)
                acc[mt][nt] = __builtin_amdgcn_mfma_f32_16x16x32_bf16(af[mt], bf[nt], acc[mt][nt], 0, 0, 0);
        __builtin_amdgcn_s_barrier();                    // all reads of cur buf done
    }
    // epilogue tile 31 (buf 1)
    asm volatile("s_waitcnt vmcnt(0)" ::: "memory");
    __builtin_amdgcn_s_barrier();
    __builtin_amdgcn_sched_barrier(0);
    {
        const unsigned short* cA = (const unsigned short*)sA + 4096;
        const unsigned short* cB = (const unsigned short*)sB + 8192;
        s16x8 af[4], bf[4];
        #pragma unroll
        for (int mt = 0; mt < 4; ++mt) {
            int row = wm + mt * 16 + ln16;
            af[mt] = *(const s16x8*)(cA + row * 32 + ((q ^ ((row >> 1) & 3)) << 3));
        }
        #pragma unroll
        for (int nt = 0; nt < 4; ++nt) {
            int row = wn + nt * 16 + ln16;
            bf[nt] = *(const s16x8*)(cB + row * 32 + ((q ^ ((row >> 1) & 3)) << 3));
        }
        #pragma unroll
        for (int mt = 0; mt < 4; ++mt)
            #pragma unroll
            for (int nt = 0; nt < 4; ++nt)
                acc[mt][nt] = __builtin_amdgcn_mfma_f32_16x16x32_bf16(af[mt], bf[nt], acc[mt][nt], 0, 0, 0);
    }

    // epilogue: +bias, relu, sumsq over s (cross-wave LDS), l2norm, mask, store
    float bv[4];
    #pragma unroll
    for (int nt = 0; nt < 4; ++nt) bv[nt] = bias[wn + nt * 16 + ln16];
    #pragma unroll
    for (int mt = 0; mt < 4; ++mt)
        #pragma unroll
        for (int j = 0; j < 4; ++j) {
            float s = 0.f;
            #pragma unroll
            for (int nt = 0; nt < 4; ++nt) {
                float v = acc[mt][nt][j] + bv[nt];
                v = fmaxf(v, 0.f);
                acc[mt][nt][j] = v;
                s += v * v;
            }
            #pragma unroll
            for (int o = 1; o < 16; o <<= 1) s += __shfl_xor(s, o, 64);
            if (ln16 == 0) atomicAdd(&s_sum[wm + mt * 16 + q * 4 + j], s);
        }
    __syncthreads();
    if (tid < 128) {
        int grow = m0 + tid;
        int c = grow / (I_N * L_N);
        int l = grow % L_N;
        float inv = 1.f / (sqrtf(s_sum[tid]) + 1e-8f);
        s_sum[tid] = (l < cap_lens[c]) ? inv : 0.f;
    }
    __syncthreads();
    #pragma unroll
    for (int mt = 0; mt < 4; ++mt)
        #pragma unroll
        for (int j = 0; j < 4; ++j) {
            const int rt = wm + mt * 16 + q * 4 + j;
            const float sc = s_sum[rt];
            #pragma unroll
            for (int nt = 0; nt < 4; ++nt)
                __builtin_nontemporal_store(acc[mt][nt][j] * sc,
                    &out[(size_t)(m0 + rt) * S_N + wn + nt * 16 + ln16]);
        }
}

extern "C" void kernel_launch(void* const* d_in, const int* in_sizes, int n_in,
                              void* d_out, int out_size, void* d_ws, size_t ws_size,
                              hipStream_t stream) {
    const float* img  = (const float*)d_in[0];
    const float* cap  = (const float*)d_in[1];
    const int*   lens = (const int*)d_in[2];
    const float* W    = (const float*)d_in[5];
    const float* bias = (const float*)d_in[6];
    float* out = (float*)d_out;
    unsigned short* ws = (unsigned short*)d_ws;

    k_convert<<<10240, 256, 0, stream>>>(img, cap, W, ws);
    dim3 gridT(16, I_N);
    k_imt<<<gridT, 256, 0, stream>>>(img, ws + OFF_IMT);
    k_gram<<<I_N, 64, 0, stream>>>(ws, ws + OFF_G);

    dim3 gridP(8, I_N);   // 512 blocks; kernel decodes (oct,i) with XCD-tile remap
    k_pre<<<gridP, 512, 0, stream>>>(ws, ws + OFF_CAP, ws + OFF_IMT, ws + OFF_G,
                                     ws + OFF_SIM);

    k_gemm3<<<M_ALL / 128, 512, 0, stream>>>(ws + OFF_SIM, ws + OFF_WT, lens, bias, out);
}

// Round 9
// 508.680 us; speedup vs baseline: 2.1696x; 1.0252x over previous
//
#include <hip/hip_runtime.h>

#define C_N 64
#define I_N 64
#define R_N 36
#define L_N 40
#define D_N 1024
#define S_N 256

#define P_LD 72   // p row stride (shorts): 144 B, 16B-aligned rows

// ws layout (shorts):
#define OFF_CAP 2359296               // img end
#define OFF_WT  4980736               // cap end: wt_t [ch:32][s:256][e':32] (K-major, e'-permuted)
#define OFF_IMT 5242880               // wt end: img_t [i][d][r48]
#define OFF_SLK 8388608               // imt end: 64 zero shorts (slack)
#define OFF_SIM 8388672               // sim_t [ch:32][m:163840][e':32] bf16 (K-major, e'-permuted)
#define M_ALL   (C_N * I_N * L_N)
#define CH_STRIDE ((size_t)M_ALL * 32)   // shorts per sim_t chunk plane
#define OFF_G   (OFF_SIM + 32 * CH_STRIDE)  // gram G [i][48][64] bf16 (0.4 MB)

// e' permutation within a 32-K chunk: e' = q*8 + md*4 + j  (d_in_chunk = md*16+q*4+j)
// -> each lane's 8 sim/wt values for its MFMA K-group are CONTIGUOUS 16B.

typedef float f4 __attribute__((ext_vector_type(4)));
typedef short s16x8 __attribute__((ext_vector_type(8)));
typedef short s16x4 __attribute__((ext_vector_type(4)));

__device__ __forceinline__ unsigned short f2bs(float f) {
    union { float f; unsigned u; } v; v.f = f;
    unsigned r = v.u + 0x7FFFu + ((v.u >> 16) & 1u);
    return (unsigned short)(r >> 16);
}
__device__ __forceinline__ float bs2f(unsigned short s) {
    union { unsigned u; float f; } v; v.u = ((unsigned)s) << 16;
    return v.f;
}
__device__ __forceinline__ void async16(const unsigned short* g, unsigned short* l) {
    __builtin_amdgcn_global_load_lds(
        (const __attribute__((address_space(1))) unsigned int*)g,
        (__attribute__((address_space(3))) unsigned int*)l, 16, 0, 0);
}

// ---------------- K0: linear converts ----------------
__global__ void k_convert(const float* __restrict__ img, const float* __restrict__ cap,
                          const float* __restrict__ W, unsigned short* __restrict__ ws) {
    int t = blockIdx.x * 256 + threadIdx.x;
    if (t < I_N * R_N * D_N) ws[t] = f2bs(img[t]);
    if (t < C_N * L_N * D_N) ws[OFF_CAP + t] = f2bs(cap[t]);
    if (t < D_N * S_N) {                       // W[d][s] -> wt_t[ch][s][e'(d)]
        int d = t >> 8, s = t & 255;
        int ch = d >> 5, wi = d & 31;
        int md = wi >> 4, r = wi & 15, q = r >> 2, j = r & 3;
        int ep = q * 8 + md * 4 + j;
        ws[OFF_WT + ((ch * 256 + s) * 32) + ep] = f2bs(W[t]);
    }
    if (t < 64) ws[OFF_SLK + t] = 0;
}

// ---------------- K0b: img [i][r][d] f32 -> imt [i][d][r48] bf16, LDS-tiled ----------
__global__ __launch_bounds__(256)
void k_imt(const float* __restrict__ img, unsigned short* __restrict__ imt) {
    __shared__ unsigned short t[64][50];
    const int i = blockIdx.y, d0 = blockIdx.x * 64;
    const int tid = threadIdx.x;
    #pragma unroll
    for (int it = 0; it < 9; ++it) {           // 36 r x 64 dc
        int e = it * 256 + tid;
        int r = e >> 6, dc = e & 63;
        t[dc][r] = f2bs(img[((size_t)i * R_N + r) * D_N + d0 + dc]);
    }
    #pragma unroll
    for (int it = 0; it < 3; ++it) {           // zero r 36..47
        int e = it * 256 + tid;
        t[e & 63][36 + (e >> 6)] = 0;
    }
    __syncthreads();
    #pragma unroll
    for (int it = 0; it < 6; ++it) {           // 64 rows x 24 dwords, contiguous
        int e = it * 256 + tid;
        int dc = e / 24, wd = e - dc * 24;
        unsigned v = (unsigned)t[dc][2 * wd] | ((unsigned)t[dc][2 * wd + 1] << 16);
        ((unsigned*)imt)[(size_t)(i * D_N + d0 + dc) * 24 + wd] = v;
    }
}

// ---------------- K0c: per-image Gram G = A.A^T ----------------
__global__ __launch_bounds__(64)
void k_gram(const unsigned short* __restrict__ img_b, unsigned short* __restrict__ g) {
    const int i = blockIdx.x;
    const int lane = threadIdx.x;
    const int q = lane >> 4, ln16 = lane & 15;
    const unsigned short* ai = img_b + i * (R_N * D_N);
    unsigned short* gi = g + i * (48 * 64);
    for (int e = lane; e < 48 * 8; e += 64) {        // zero cols 48..63
        int r = e >> 3, wd = e & 7;
        ((unsigned*)(gi + r * 64 + 48))[wd] = 0;
    }
    f4 c[3][3] = {};
    #pragma unroll 4
    for (int ks = 0; ks < 32; ++ks) {
        const int kb = ks * 32 + q * 8;
        s16x8 af[3];
        af[0] = *(const s16x8*)(ai + ln16 * D_N + kb);
        af[1] = *(const s16x8*)(ai + (16 + ln16) * D_N + kb);
        af[2] = (ln16 < 4) ? *(const s16x8*)(ai + (32 + ln16) * D_N + kb) : (s16x8)0;
        #pragma unroll
        for (int mt = 0; mt < 3; ++mt)
            #pragma unroll
            for (int nt = 0; nt < 3; ++nt)
                c[mt][nt] = __builtin_amdgcn_mfma_f32_16x16x32_bf16(af[mt], af[nt], c[mt][nt], 0, 0, 0);
    }
    #pragma unroll
    for (int mt = 0; mt < 3; ++mt)
        #pragma unroll
        for (int nt = 0; nt < 3; ++nt)
            #pragma unroll
            for (int j = 0; j < 4; ++j)
                gi[(mt * 16 + q * 4 + j) * 64 + nt * 16 + ln16] = f2bs(c[mt][nt][j]);
}

// ---------------- A: one WAVE per (c,i). Gram quadform for wc-norm; GEMM2 single
// pass; sim stores e'-permuted -> each lane stores ONE contiguous 16B s16x8
// (full-line write combining; was 2x 8B partial-line pieces -> 374MB WRITE for
// a 320MB sim).
__global__ __launch_bounds__(512, 4)
void k_pre(const unsigned short* __restrict__ img_b,
           const unsigned short* __restrict__ cap_b,
           const unsigned short* __restrict__ img_t,
           const unsigned short* __restrict__ gram,
           unsigned short* __restrict__ simg) {
    __shared__ __align__(16) unsigned short s_p[8][48 * P_LD];   // 55296 B

    const int n = blockIdx.y * 8 + blockIdx.x;       // linear id; XCD = n & 7
    const int x = n & 7, m = n >> 3;
    const int i   = ((x & 3) << 4) | (m >> 2);       // 16 images per XCD
    const int oct = ((x >> 2) << 2) | (m & 3);       // 4 octets per XCD
    const int wave = threadIdx.x >> 6, lane = threadIdx.x & 63;
    const int c = oct * 8 + wave;
    const int pair = c * I_N + i;
    const int q = lane >> 4, ln16 = lane & 15;

    const unsigned short* ai = img_b + i * (R_N * D_N);          // GEMM1 A (m=r)
    const unsigned short* bc = cap_b + c * (L_N * D_N);          // GEMM1 B (n=l), sim cap
    const unsigned short* imtc = img_t + (size_t)i * D_N * 48;   // GEMM2 A (m=d,k=r)
    unsigned short* sp = &s_p[wave][0];

    // zero own p slot (covers m-pad rows 40..47 and k-pad cols 36..71)
    for (int k = lane; k < 48 * P_LD / 2; k += 64) ((unsigned*)sp)[k] = 0;

    // ---- GEMM1: attn[r][l], full K=1024 in this wave ----
    f4 acc[3][3] = {};
    #pragma unroll 4
    for (int ks = 0; ks < 32; ++ks) {
        const int kb = ks * 32 + q * 8;
        s16x8 af[3], bf[3];
        af[0] = *(const s16x8*)(ai + ln16 * D_N + kb);
        af[1] = *(const s16x8*)(ai + (16 + ln16) * D_N + kb);
        af[2] = (ln16 < 4) ? *(const s16x8*)(ai + (32 + ln16) * D_N + kb) : (s16x8)0;
        bf[0] = *(const s16x8*)(bc + ln16 * D_N + kb);
        bf[1] = *(const s16x8*)(bc + (16 + ln16) * D_N + kb);
        bf[2] = (ln16 < 8) ? *(const s16x8*)(bc + (32 + ln16) * D_N + kb) : (s16x8)0;
        #pragma unroll
        for (int mt = 0; mt < 3; ++mt)
            #pragma unroll
            for (int nt = 0; nt < 3; ++nt)
                acc[mt][nt] = __builtin_amdgcn_mfma_f32_16x16x32_bf16(af[mt], bf[nt], acc[mt][nt], 0, 0, 0);
    }

    // ---- leaky relu ----
    #pragma unroll
    for (int mt = 0; mt < 3; ++mt)
        #pragma unroll
        for (int nt = 0; nt < 3; ++nt)
            #pragma unroll
            for (int j = 0; j < 4; ++j) {
                float v = acc[mt][nt][j];
                acc[mt][nt][j] = (v > 0.f) ? v : 0.1f * v;
            }
    // ---- l2norm over words l per region row r ----
    #pragma unroll
    for (int mt = 0; mt < 3; ++mt)
        #pragma unroll
        for (int j = 0; j < 4; ++j) {
            float ss = 0.f;
            #pragma unroll
            for (int nt = 0; nt < 3; ++nt) ss += acc[mt][nt][j] * acc[mt][nt][j];
            #pragma unroll
            for (int o = 1; o < 16; o <<= 1) ss += __shfl_xor(ss, o, 64);
            float inv = 1.f / (sqrtf(ss) + 1e-8f);
            #pragma unroll
            for (int nt = 0; nt < 3; ++nt) acc[mt][nt][j] *= inv;
        }
    // ---- softmax over regions r per word l; store p[l][r] to LDS ----
    #pragma unroll
    for (int nt = 0; nt < 3; ++nt) {
        const int l = nt * 16 + ln16;
        float mx = -1e30f;
        #pragma unroll
        for (int mt = 0; mt < 3; ++mt)
            #pragma unroll
            for (int j = 0; j < 4; ++j) {
                int r = mt * 16 + q * 4 + j;
                if (r < R_N) mx = fmaxf(mx, 9.f * acc[mt][nt][j]);
            }
        mx = fmaxf(mx, __shfl_xor(mx, 16, 64));
        mx = fmaxf(mx, __shfl_xor(mx, 32, 64));
        float sum = 0.f;
        #pragma unroll
        for (int mt = 0; mt < 3; ++mt)
            #pragma unroll
            for (int j = 0; j < 4; ++j) {
                int r = mt * 16 + q * 4 + j;
                float e = (r < R_N) ? __expf(9.f * acc[mt][nt][j] - mx) : 0.f;
                acc[mt][nt][j] = e;
                sum += e;
            }
        sum += __shfl_xor(sum, 16, 64);
        sum += __shfl_xor(sum, 32, 64);
        float inv = 1.f / sum;
        #pragma unroll
        for (int mt = 0; mt < 3; ++mt)
            #pragma unroll
            for (int j = 0; j < 4; ++j) {
                int r = mt * 16 + q * 4 + j;
                if (r < R_N && l < L_N) sp[l * P_LD + r] = f2bs(acc[mt][nt][j] * inv);
            }
    }
    // same-wave DS ordering: reads below see the writes (no barrier needed).

    // ---- GEMM2 p-fragments once: used as B operand [n=l][k=r] ----
    s16x8 paf[3][2];
    #pragma unroll
    for (int nl = 0; nl < 3; ++nl)
        #pragma unroll
        for (int ks = 0; ks < 2; ++ks)
            paf[nl][ks] = *(const s16x8*)(sp + (nl * 16 + ln16) * P_LD + ks * 32 + q * 8);

    // ---- Gram quadform: rs[l] = p_l^T G p_l ----
    const unsigned short* gi = gram + i * (48 * 64);
    f4 T[3][3] = {};
    #pragma unroll
    for (int ks = 0; ks < 2; ++ks) {
        const int kb = ks * 32 + q * 8;
        s16x8 ga[3];
        #pragma unroll
        for (int mt = 0; mt < 3; ++mt)
            ga[mt] = *(const s16x8*)(gi + (mt * 16 + ln16) * 64 + kb);
        #pragma unroll
        for (int mt = 0; mt < 3; ++mt)
            #pragma unroll
            for (int nl = 0; nl < 3; ++nl)
                T[mt][nl] = __builtin_amdgcn_mfma_f32_16x16x32_bf16(ga[mt], paf[nl][ks], T[mt][nl], 0, 0, 0);
    }
    float inv2[3];
    #pragma unroll
    for (int nl = 0; nl < 3; ++nl) {
        const int l = nl * 16 + ln16;
        float rsl = 0.f;
        #pragma unroll
        for (int mt = 0; mt < 3; ++mt) {
            const s16x4 pv = *(const s16x4*)(sp + l * P_LD + mt * 16 + q * 4);
            #pragma unroll
            for (int j = 0; j < 4; ++j)
                rsl += bs2f((unsigned short)pv[j]) * T[mt][nl][j];
        }
        rsl += __shfl_xor(rsl, 16, 64);
        rsl += __shfl_xor(rsl, 32, 64);
        inv2[nl] = 1.f / (sqrtf(rsl) + 1e-8f);
    }

    // ---- GEMM2: sim=(wc*inv-cap)^2 -> sim_t[ch][pair*40+l][e'] (16B/lane stores) ----
    #pragma unroll 2
    for (int ch = 0; ch < 32; ++ch) {
        f4 a2[2][3] = {};
        #pragma unroll
        for (int ks = 0; ks < 2; ++ks) {
            const int kb = ks * 32 + q * 8;
            #pragma unroll
            for (int md = 0; md < 2; ++md) {
                const int drow = ch * 32 + md * 16 + ln16;
                s16x8 afr = *(const s16x8*)(imtc + drow * 48 + kb);
                #pragma unroll
                for (int nl = 0; nl < 3; ++nl)
                    a2[md][nl] = __builtin_amdgcn_mfma_f32_16x16x32_bf16(afr, paf[nl][ks], a2[md][nl], 0, 0, 0);
            }
        }
        const size_t chbase = (size_t)ch * CH_STRIDE + (size_t)pair * L_N * 32;
        #pragma unroll
        for (int nl = 0; nl < 3; ++nl) {
            const int l = nl * 16 + ln16;
            if (l < L_N) {
                const float iv = inv2[nl];
                s16x8 ov;
                #pragma unroll
                for (int md = 0; md < 2; ++md) {
                    const int db = ch * 32 + md * 16 + q * 4;    // global d of j=0
                    const s16x4 cv = *(const s16x4*)(bc + l * D_N + db);
                    #pragma unroll
                    for (int j = 0; j < 4; ++j) {
                        float dv = a2[md][nl][j] * iv - bs2f((unsigned short)cv[j]);
                        ov[md * 4 + j] = (short)f2bs(dv * dv);   // e' = q*8+md*4+j
                    }
                }
                __builtin_nontemporal_store(ov,
                    (s16x8*)(simg + chbase + (size_t)l * 32 + q * 8));
            }
        }
    }
}

// ---------------- B: GEMM3  out = l2norm(relu(sim @ W + b)) * mask ----------------
// K-major e'-permuted layouts; counted-vmcnt dbuf; REVERSE ch traversal (31->0):
// the most-recently-written sim planes are still L3-resident -> read them first
// (sim 320MB > 256MB L3; forward order = LRU streaming = ~100% miss).
__global__ __launch_bounds__(512, 4)
void k_gemm3(const unsigned short* __restrict__ simt,
             const unsigned short* __restrict__ wtt,
             const int* __restrict__ cap_lens,
             const float* __restrict__ bias,
             float* __restrict__ out) {
    __shared__ __align__(16) unsigned short sA[2][128 * 32];   // 8 KB x2
    __shared__ __align__(16) unsigned short sB[2][256 * 32];   // 16 KB x2
    __shared__ float s_sum[128];

    const int tid = threadIdx.x;
    const int w = tid >> 6, lane = tid & 63;
    const int ln16 = lane & 15, q = lane >> 4;
    const int wm = (w >> 2) * 64, wn = (w & 3) * 64;
    const int m0 = blockIdx.x * 128;
    // staging: thread -> (row = tid>>2, slot = tid&3); source chunk pre-swizzled
    const int srow = tid >> 2;
    const int swz = ((tid & 3) ^ ((srow >> 1) & 3)) << 3;      // shorts
    const unsigned short* gA  = simt + ((size_t)(m0 + srow)) * 32 + swz;  // + ch*CH_STRIDE
    const unsigned short* gB0 = wtt + (size_t)srow * 32 + swz;            // + ch*8192
    const unsigned short* gB1 = wtt + (size_t)(128 + srow) * 32 + swz;
    unsigned short* const lA = (unsigned short*)sA + tid * 8;             // + buf*4096
    unsigned short* const lB = (unsigned short*)sB + tid * 8;             // + buf*8192 (+4096 for B1)

    if (tid < 128) s_sum[tid] = 0.f;

    // prologue: stage tile ch=31 into buf 0
    async16(gA + (size_t)31 * CH_STRIDE, lA);
    async16(gB0 + 31 * 8192, lB);
    async16(gB1 + 31 * 8192, lB + 4096);

    f4 acc[4][4] = {};
    #pragma unroll 1
    for (int t = 0; t < 31; ++t) {            // compute ch=31-t; prefetch ch=30-t
        const int nb = (t + 1) & 1;
        const int pch = 30 - t;
        async16(gA + (size_t)pch * CH_STRIDE, lA + nb * 4096);
        async16(gB0 + pch * 8192, lB + nb * 8192);
        async16(gB1 + pch * 8192, lB + nb * 8192 + 4096);
        asm volatile("s_waitcnt vmcnt(3)" ::: "memory"); // cur tile landed; next in flight
        __builtin_amdgcn_s_barrier();
        __builtin_amdgcn_sched_barrier(0);
        const unsigned short* cA = (const unsigned short*)sA + (t & 1) * 4096;
        const unsigned short* cB = (const unsigned short*)sB + (t & 1) * 8192;
        s16x8 af[4], bf[4];
        #pragma unroll
        for (int mt = 0; mt < 4; ++mt) {
            int row = wm + mt * 16 + ln16;
            af[mt] = *(const s16x8*)(cA + row * 32 + ((q ^ ((row >> 1) & 3)) << 3));
        }
        #pragma unroll
        for (int nt = 0; nt < 4; ++nt) {
            int row = wn + nt * 16 + ln16;
            bf[nt] = *(const s16x8*)(cB + row * 32 + ((q ^ ((row >> 1) & 3)) << 3));
        }
        #pragma unroll
        for (int mt = 0; mt < 4; ++mt)
            #pragma unroll
            for (int nt = 0; nt < 4; ++nt)
                acc[mt][nt] = __builtin_amdgcn_mfma_f32_16x16x32_bf16(af[mt], bf[nt], acc[mt][nt], 0, 0, 0);
        __builtin_amdgcn_s_barrier();                    // all reads of cur buf done
    }
    // epilogue tile ch=0 (buf 1)
    asm volatile("s_waitcnt vmcnt(0)" ::: "memory");
    __builtin_amdgcn_s_barrier();
    __builtin_amdgcn_sched_barrier(0);
    {
        const unsigned short* cA = (const unsigned short*)sA + 4096;
        const unsigned short* cB = (const unsigned short*)sB + 8192;
        s16x8 af[4], bf[4];
        #pragma unroll
        for (int mt = 0; mt < 4; ++mt) {
            int row = wm + mt * 16 + ln16;
            af[mt] = *(const s16x8*)(cA + row * 32 + ((q ^ ((row >> 1) & 3)) << 3));
        }
        #pragma unroll
        for (int nt = 0; nt < 4; ++nt) {
            int row = wn + nt * 16 + ln16;
            bf[nt] = *(const s16x8*)(cB + row * 32 + ((q ^ ((row >> 1) & 3)) << 3));
        }
        #pragma unroll
        for (int mt = 0; mt < 4; ++mt)
            #pragma unroll
            for (int nt = 0; nt < 4; ++nt)
                acc[mt][nt] = __builtin_amdgcn_mfma_f32_16x16x32_bf16(af[mt], bf[nt], acc[mt][nt], 0, 0, 0);
    }

    // epilogue: +bias, relu, sumsq over s (cross-wave LDS), l2norm, mask, store
    float bv[4];
    #pragma unroll
    for (int nt = 0; nt < 4; ++nt) bv[nt] = bias[wn + nt * 16 + ln16];
    #pragma unroll
    for (int mt = 0; mt < 4; ++mt)
        #pragma unroll
        for (int j = 0; j < 4; ++j) {
            float s = 0.f;
            #pragma unroll
            for (int nt = 0; nt < 4; ++nt) {
                float v = acc[mt][nt][j] + bv[nt];
                v = fmaxf(v, 0.f);
                acc[mt][nt][j] = v;
                s += v * v;
            }
            #pragma unroll
            for (int o = 1; o < 16; o <<= 1) s += __shfl_xor(s, o, 64);
            if (ln16 == 0) atomicAdd(&s_sum[wm + mt * 16 + q * 4 + j], s);
        }
    __syncthreads();
    if (tid < 128) {
        int grow = m0 + tid;
        int c = grow / (I_N * L_N);
        int l = grow % L_N;
        float inv = 1.f / (sqrtf(s_sum[tid]) + 1e-8f);
        s_sum[tid] = (l < cap_lens[c]) ? inv : 0.f;
    }
    __syncthreads();
    #pragma unroll
    for (int mt = 0; mt < 4; ++mt)
        #pragma unroll
        for (int j = 0; j < 4; ++j) {
            const int rt = wm + mt * 16 + q * 4 + j;
            const float sc = s_sum[rt];
            #pragma unroll
            for (int nt = 0; nt < 4; ++nt)
                __builtin_nontemporal_store(acc[mt][nt][j] * sc,
                    &out[(size_t)(m0 + rt) * S_N + wn + nt * 16 + ln16]);
        }
}

extern "C" void kernel_launch(void* const* d_in, const int* in_sizes, int n_in,
                              void* d_out, int out_size, void* d_ws, size_t ws_size,
                              hipStream_t stream) {
    const float* img  = (const float*)d_in[0];
    const float* cap  = (const float*)d_in[1];
    const int*   lens = (const int*)d_in[2];
    const float* W    = (const float*)d_in[5];
    const float* bias = (const float*)d_in[6];
    float* out = (float*)d_out;
    unsigned short* ws = (unsigned short*)d_ws;

    k_convert<<<10240, 256, 0, stream>>>(img, cap, W, ws);
    dim3 gridT(16, I_N);
    k_imt<<<gridT, 256, 0, stream>>>(img, ws + OFF_IMT);
    k_gram<<<I_N, 64, 0, stream>>>(ws, ws + OFF_G);

    dim3 gridP(8, I_N);   // 512 blocks; kernel decodes (oct,i) with XCD-tile remap
    k_pre<<<gridP, 512, 0, stream>>>(ws, ws + OFF_CAP, ws + OFF_IMT, ws + OFF_G,
                                     ws + OFF_SIM);

    k_gemm3<<<M_ALL / 128, 512, 0, stream>>>(ws + OFF_SIM, ws + OFF_WT, lens, bias, out);
}

// Round 10
// 476.980 us; speedup vs baseline: 2.3138x; 1.0665x over previous
//
#include <hip/hip_runtime.h>

#define C_N 64
#define I_N 64
#define R_N 36
#define L_N 40
#define D_N 1024
#define S_N 256

#define P_LD 72   // p row stride (shorts): 144 B, 16B-aligned rows

// ws layout (shorts):
#define OFF_CAP 2359296               // img end
#define OFF_WT  4980736               // cap end: wt_t [ch:32][s:256][e':32] (K-major, e'-permuted)
#define OFF_IMT 5242880               // wt end: img_t [i][d][r48]
#define OFF_SLK 8388608               // imt end: 64 zero shorts (slack)
#define OFF_SIM 8388672               // sim_t [ch:32][m:163840][e':32] bf16 (compact rows used)
#define M_ALL   (C_N * I_N * L_N)
#define CH_STRIDE ((size_t)M_ALL * 32)   // shorts per sim_t chunk plane (worst-case sized)
#define OFF_G   (OFF_SIM + 32 * CH_STRIDE)  // gram G [i][48][64] bf16
#define OFF_P   (OFF_G + I_N * 48 * 64)     // int P[65] prefix of cap_lens (cast)

typedef float f4 __attribute__((ext_vector_type(4)));
typedef short s16x8 __attribute__((ext_vector_type(8)));
typedef short s16x4 __attribute__((ext_vector_type(4)));

__device__ __forceinline__ unsigned short f2bs(float f) {
    union { float f; unsigned u; } v; v.f = f;
    unsigned r = v.u + 0x7FFFu + ((v.u >> 16) & 1u);
    return (unsigned short)(r >> 16);
}
__device__ __forceinline__ float bs2f(unsigned short s) {
    union { unsigned u; float f; } v; v.u = ((unsigned)s) << 16;
    return v.f;
}
__device__ __forceinline__ void async16(const unsigned short* g, unsigned short* l) {
    __builtin_amdgcn_global_load_lds(
        (const __attribute__((address_space(1))) unsigned int*)g,
        (__attribute__((address_space(3))) unsigned int*)l, 16, 0, 0);
}

// ---------------- K0: linear converts ----------------
__global__ void k_convert(const float* __restrict__ img, const float* __restrict__ cap,
                          const float* __restrict__ W, unsigned short* __restrict__ ws) {
    int t = blockIdx.x * 256 + threadIdx.x;
    if (t < I_N * R_N * D_N) ws[t] = f2bs(img[t]);
    if (t < C_N * L_N * D_N) ws[OFF_CAP + t] = f2bs(cap[t]);
    if (t < D_N * S_N) {                       // W[d][s] -> wt_t[ch][s][e'(d)]
        int d = t >> 8, s = t & 255;
        int ch = d >> 5, wi = d & 31;
        int md = wi >> 4, r = wi & 15, q = r >> 2, j = r & 3;
        int ep = q * 8 + md * 4 + j;
        ws[OFF_WT + ((ch * 256 + s) * 32) + ep] = f2bs(W[t]);
    }
    if (t < 64) ws[OFF_SLK + t] = 0;
}

// ---------------- K0s: prefix-scan of cap_lens -> P[0..64] ----------------
__global__ void k_scan(const int* __restrict__ lens, int* __restrict__ P) {
    if (threadIdx.x == 0) {
        int a = 0;
        for (int c = 0; c < C_N; ++c) { P[c] = a; a += lens[c]; }
        P[C_N] = a;
    }
}

// ---------------- K0z: zero the masked out rows (l >= len) ----------------
__global__ __launch_bounds__(256)
void k_zero(const int* __restrict__ lens, float* __restrict__ out) {
    int idx = blockIdx.x * 256 + threadIdx.x;
    int row = idx >> 6, sq = (idx & 63) << 2;
    int c = row / (I_N * L_N);
    int l = row % L_N;
    if (l >= lens[c]) {
        f4 z = {};
        __builtin_nontemporal_store(z, (f4*)(out + (size_t)row * S_N + sq));
    }
}

// ---------------- K0b: img [i][r][d] f32 -> imt [i][d][r48] bf16, LDS-tiled ----------
__global__ __launch_bounds__(256)
void k_imt(const float* __restrict__ img, unsigned short* __restrict__ imt) {
    __shared__ unsigned short t[64][50];
    const int i = blockIdx.y, d0 = blockIdx.x * 64;
    const int tid = threadIdx.x;
    #pragma unroll
    for (int it = 0; it < 9; ++it) {           // 36 r x 64 dc
        int e = it * 256 + tid;
        int r = e >> 6, dc = e & 63;
        t[dc][r] = f2bs(img[((size_t)i * R_N + r) * D_N + d0 + dc]);
    }
    #pragma unroll
    for (int it = 0; it < 3; ++it) {           // zero r 36..47
        int e = it * 256 + tid;
        t[e & 63][36 + (e >> 6)] = 0;
    }
    __syncthreads();
    #pragma unroll
    for (int it = 0; it < 6; ++it) {           // 64 rows x 24 dwords, contiguous
        int e = it * 256 + tid;
        int dc = e / 24, wd = e - dc * 24;
        unsigned v = (unsigned)t[dc][2 * wd] | ((unsigned)t[dc][2 * wd + 1] << 16);
        ((unsigned*)imt)[(size_t)(i * D_N + d0 + dc) * 24 + wd] = v;
    }
}

// ---------------- K0c: per-image Gram G = A.A^T ----------------
__global__ __launch_bounds__(64)
void k_gram(const unsigned short* __restrict__ img_b, unsigned short* __restrict__ g) {
    const int i = blockIdx.x;
    const int lane = threadIdx.x;
    const int q = lane >> 4, ln16 = lane & 15;
    const unsigned short* ai = img_b + i * (R_N * D_N);
    unsigned short* gi = g + i * (48 * 64);
    for (int e = lane; e < 48 * 8; e += 64) {        // zero cols 48..63
        int r = e >> 3, wd = e & 7;
        ((unsigned*)(gi + r * 64 + 48))[wd] = 0;
    }
    f4 c[3][3] = {};
    #pragma unroll 4
    for (int ks = 0; ks < 32; ++ks) {
        const int kb = ks * 32 + q * 8;
        s16x8 af[3];
        af[0] = *(const s16x8*)(ai + ln16 * D_N + kb);
        af[1] = *(const s16x8*)(ai + (16 + ln16) * D_N + kb);
        af[2] = (ln16 < 4) ? *(const s16x8*)(ai + (32 + ln16) * D_N + kb) : (s16x8)0;
        #pragma unroll
        for (int mt = 0; mt < 3; ++mt)
            #pragma unroll
            for (int nt = 0; nt < 3; ++nt)
                c[mt][nt] = __builtin_amdgcn_mfma_f32_16x16x32_bf16(af[mt], af[nt], c[mt][nt], 0, 0, 0);
    }
    #pragma unroll
    for (int mt = 0; mt < 3; ++mt)
        #pragma unroll
        for (int nt = 0; nt < 3; ++nt)
            #pragma unroll
            for (int j = 0; j < 4; ++j)
                gi[(mt * 16 + q * 4 + j) * 64 + nt * 16 + ln16] = f2bs(c[mt][nt][j]);
}

// ---------------- A: one WAVE per (c,i), length-aware (NL = live l-tiles) and
// COMPACT sim rows: row = P[c]*64 + i*len + l, only l < len stored. Dead l-tiles
// skipped in GEMM1/softmax/quadform/GEMM2 (wave-uniform branches).
__global__ __launch_bounds__(512, 4)
void k_pre(const unsigned short* __restrict__ img_b,
           const unsigned short* __restrict__ cap_b,
           const unsigned short* __restrict__ img_t,
           const unsigned short* __restrict__ gram,
           const int* __restrict__ lens,
           const int* __restrict__ P,
           unsigned short* __restrict__ simg) {
    __shared__ __align__(16) unsigned short s_p[8][48 * P_LD];   // 55296 B

    const int n = blockIdx.y * 8 + blockIdx.x;       // linear id; XCD = n & 7
    const int x = n & 7, m = n >> 3;
    const int i   = ((x & 3) << 4) | (m >> 2);       // 16 images per XCD
    const int oct = ((x >> 2) << 2) | (m & 3);       // 4 octets per XCD
    const int wave = threadIdx.x >> 6, lane = threadIdx.x & 63;
    const int c = oct * 8 + wave;
    const int q = lane >> 4, ln16 = lane & 15;

    const int len = lens[c];
    const int NL = (len > 32) ? 3 : (len > 16 ? 2 : 1);
    const int rowbase = P[c] * 64 + i * len;         // compact sim row base

    const unsigned short* ai = img_b + i * (R_N * D_N);          // GEMM1 A (m=r)
    const unsigned short* bc = cap_b + c * (L_N * D_N);          // GEMM1 B (n=l), sim cap
    const unsigned short* imtc = img_t + (size_t)i * D_N * 48;   // GEMM2 A (m=d,k=r)
    unsigned short* sp = &s_p[wave][0];

    // zero own p slot (covers m-pad rows 40..47 and k-pad cols 36..71)
    for (int k = lane; k < 48 * P_LD / 2; k += 64) ((unsigned*)sp)[k] = 0;

    // ---- GEMM1: attn[r][l], full K=1024; dead l-tiles (nt >= NL) skipped ----
    f4 acc[3][3] = {};
    #pragma unroll 4
    for (int ks = 0; ks < 32; ++ks) {
        const int kb = ks * 32 + q * 8;
        s16x8 af[3], bf[3];
        af[0] = *(const s16x8*)(ai + ln16 * D_N + kb);
        af[1] = *(const s16x8*)(ai + (16 + ln16) * D_N + kb);
        af[2] = (ln16 < 4) ? *(const s16x8*)(ai + (32 + ln16) * D_N + kb) : (s16x8)0;
        bf[0] = *(const s16x8*)(bc + ln16 * D_N + kb);
        bf[1] = (NL > 1) ? *(const s16x8*)(bc + (16 + ln16) * D_N + kb) : (s16x8)0;
        bf[2] = (NL > 2 && ln16 < 8) ? *(const s16x8*)(bc + (32 + ln16) * D_N + kb) : (s16x8)0;
        #pragma unroll
        for (int mt = 0; mt < 3; ++mt)
            #pragma unroll
            for (int nt = 0; nt < 3; ++nt)
                if (nt < NL)
                    acc[mt][nt] = __builtin_amdgcn_mfma_f32_16x16x32_bf16(af[mt], bf[nt], acc[mt][nt], 0, 0, 0);
    }

    // ---- leaky relu (zeros stay zero) ----
    #pragma unroll
    for (int mt = 0; mt < 3; ++mt)
        #pragma unroll
        for (int nt = 0; nt < 3; ++nt)
            #pragma unroll
            for (int j = 0; j < 4; ++j) {
                float v = acc[mt][nt][j];
                acc[mt][nt][j] = (v > 0.f) ? v : 0.1f * v;
            }
    // ---- l2norm over words l per region row r (masked cols contribute 0) ----
    #pragma unroll
    for (int mt = 0; mt < 3; ++mt)
        #pragma unroll
        for (int j = 0; j < 4; ++j) {
            float ss = 0.f;
            #pragma unroll
            for (int nt = 0; nt < 3; ++nt) ss += acc[mt][nt][j] * acc[mt][nt][j];
            #pragma unroll
            for (int o = 1; o < 16; o <<= 1) ss += __shfl_xor(ss, o, 64);
            float inv = 1.f / (sqrtf(ss) + 1e-8f);
            #pragma unroll
            for (int nt = 0; nt < 3; ++nt) acc[mt][nt][j] *= inv;
        }
    // ---- softmax over regions r per word l (live tiles only); p -> LDS ----
    #pragma unroll
    for (int nt = 0; nt < 3; ++nt) {
        if (nt < NL) {
            const int l = nt * 16 + ln16;
            float mx = -1e30f;
            #pragma unroll
            for (int mt = 0; mt < 3; ++mt)
                #pragma unroll
                for (int j = 0; j < 4; ++j) {
                    int r = mt * 16 + q * 4 + j;
                    if (r < R_N) mx = fmaxf(mx, 9.f * acc[mt][nt][j]);
                }
            mx = fmaxf(mx, __shfl_xor(mx, 16, 64));
            mx = fmaxf(mx, __shfl_xor(mx, 32, 64));
            float sum = 0.f;
            #pragma unroll
            for (int mt = 0; mt < 3; ++mt)
                #pragma unroll
                for (int j = 0; j < 4; ++j) {
                    int r = mt * 16 + q * 4 + j;
                    float e = (r < R_N) ? __expf(9.f * acc[mt][nt][j] - mx) : 0.f;
                    acc[mt][nt][j] = e;
                    sum += e;
                }
            sum += __shfl_xor(sum, 16, 64);
            sum += __shfl_xor(sum, 32, 64);
            float inv = 1.f / sum;
            #pragma unroll
            for (int mt = 0; mt < 3; ++mt)
                #pragma unroll
                for (int j = 0; j < 4; ++j) {
                    int r = mt * 16 + q * 4 + j;
                    if (r < R_N && l < L_N) sp[l * P_LD + r] = f2bs(acc[mt][nt][j] * inv);
                }
        }
    }
    // same-wave DS ordering: reads below see the writes (no barrier needed).

    // ---- GEMM2 p-fragments (dead rows are zero in sp) ----
    s16x8 paf[3][2];
    #pragma unroll
    for (int nl = 0; nl < 3; ++nl)
        #pragma unroll
        for (int ks = 0; ks < 2; ++ks)
            paf[nl][ks] = *(const s16x8*)(sp + (nl * 16 + ln16) * P_LD + ks * 32 + q * 8);

    // ---- Gram quadform: rs[l] = p_l^T G p_l (live tiles only) ----
    const unsigned short* gi = gram + i * (48 * 64);
    f4 T[3][3] = {};
    #pragma unroll
    for (int ks = 0; ks < 2; ++ks) {
        const int kb = ks * 32 + q * 8;
        s16x8 ga[3];
        #pragma unroll
        for (int mt = 0; mt < 3; ++mt)
            ga[mt] = *(const s16x8*)(gi + (mt * 16 + ln16) * 64 + kb);
        #pragma unroll
        for (int mt = 0; mt < 3; ++mt)
            #pragma unroll
            for (int nl = 0; nl < 3; ++nl)
                if (nl < NL)
                    T[mt][nl] = __builtin_amdgcn_mfma_f32_16x16x32_bf16(ga[mt], paf[nl][ks], T[mt][nl], 0, 0, 0);
    }
    float inv2[3] = {0.f, 0.f, 0.f};
    #pragma unroll
    for (int nl = 0; nl < 3; ++nl) {
        if (nl < NL) {
            const int l = nl * 16 + ln16;
            float rsl = 0.f;
            #pragma unroll
            for (int mt = 0; mt < 3; ++mt) {
                const s16x4 pv = *(const s16x4*)(sp + l * P_LD + mt * 16 + q * 4);
                #pragma unroll
                for (int j = 0; j < 4; ++j)
                    rsl += bs2f((unsigned short)pv[j]) * T[mt][nl][j];
            }
            rsl += __shfl_xor(rsl, 16, 64);
            rsl += __shfl_xor(rsl, 32, 64);
            inv2[nl] = 1.f / (sqrtf(rsl) + 1e-8f);
        }
    }

    // ---- GEMM2: sim=(wc*inv-cap)^2 -> compact rows, e'-permuted 16B stores ----
    #pragma unroll 2
    for (int ch = 0; ch < 32; ++ch) {
        f4 a2[2][3] = {};
        #pragma unroll
        for (int ks = 0; ks < 2; ++ks) {
            const int kb = ks * 32 + q * 8;
            #pragma unroll
            for (int md = 0; md < 2; ++md) {
                const int drow = ch * 32 + md * 16 + ln16;
                s16x8 afr = *(const s16x8*)(imtc + drow * 48 + kb);
                #pragma unroll
                for (int nl = 0; nl < 3; ++nl)
                    if (nl < NL)
                        a2[md][nl] = __builtin_amdgcn_mfma_f32_16x16x32_bf16(afr, paf[nl][ks], a2[md][nl], 0, 0, 0);
            }
        }
        const size_t chbase = (size_t)ch * CH_STRIDE + (size_t)rowbase * 32;
        #pragma unroll
        for (int nl = 0; nl < 3; ++nl) {
            if (nl < NL) {
                const int l = nl * 16 + ln16;
                if (l < len) {
                    const float iv = inv2[nl];
                    s16x8 ov;
                    #pragma unroll
                    for (int md = 0; md < 2; ++md) {
                        const int db = ch * 32 + md * 16 + q * 4;    // global d of j=0
                        const s16x4 cv = *(const s16x4*)(bc + l * D_N + db);
                        #pragma unroll
                        for (int j = 0; j < 4; ++j) {
                            float dv = a2[md][nl][j] * iv - bs2f((unsigned short)cv[j]);
                            ov[md * 4 + j] = (short)f2bs(dv * dv);   // e' = q*8+md*4+j
                        }
                    }
                    __builtin_nontemporal_store(ov,
                        (s16x8*)(simg + chbase + (size_t)l * 32 + q * 8));
                }
            }
        }
    }
}

// ---------------- B: GEMM3 on COMPACT rows; out = l2norm(relu(sim@W+b)) ------
// Blocks beyond Mv exit immediately (~36% of grid). Epilogue maps compact row
// -> (c,i,l) via binary search in P (all compact rows valid; no mask).
__global__ __launch_bounds__(512, 4)
void k_gemm3(const unsigned short* __restrict__ simt,
             const unsigned short* __restrict__ wtt,
             const int* __restrict__ P,
             const float* __restrict__ bias,
             float* __restrict__ out) {
    __shared__ __align__(16) unsigned short sA[2][128 * 32];   // 8 KB x2
    __shared__ __align__(16) unsigned short sB[2][256 * 32];   // 16 KB x2
    __shared__ float s_sum[128];

    const int m0 = blockIdx.x * 128;
    const int Mv = P[C_N] * 64;
    if (m0 >= Mv) return;                      // block entirely past valid rows

    const int tid = threadIdx.x;
    const int w = tid >> 6, lane = tid & 63;
    const int ln16 = lane & 15, q = lane >> 4;
    const int wm = (w >> 2) * 64, wn = (w & 3) * 64;
    // staging: thread -> (row = tid>>2, slot = tid&3); source chunk pre-swizzled
    const int srow = tid >> 2;
    const int swz = ((tid & 3) ^ ((srow >> 1) & 3)) << 3;      // shorts
    const unsigned short* gA  = simt + ((size_t)(m0 + srow)) * 32 + swz;  // + ch*CH_STRIDE
    const unsigned short* gB0 = wtt + (size_t)srow * 32 + swz;            // + ch*8192
    const unsigned short* gB1 = wtt + (size_t)(128 + srow) * 32 + swz;
    unsigned short* const lA = (unsigned short*)sA + tid * 8;             // + buf*4096
    unsigned short* const lB = (unsigned short*)sB + tid * 8;             // + buf*8192 (+4096 for B1)

    if (tid < 128) s_sum[tid] = 0.f;

    // prologue: stage tile ch=31 into buf 0
    async16(gA + (size_t)31 * CH_STRIDE, lA);
    async16(gB0 + 31 * 8192, lB);
    async16(gB1 + 31 * 8192, lB + 4096);

    f4 acc[4][4] = {};
    #pragma unroll 1
    for (int t = 0; t < 31; ++t) {            // compute ch=31-t; prefetch ch=30-t
        const int nb = (t + 1) & 1;
        const int pch = 30 - t;
        async16(gA + (size_t)pch * CH_STRIDE, lA + nb * 4096);
        async16(gB0 + pch * 8192, lB + nb * 8192);
        async16(gB1 + pch * 8192, lB + nb * 8192 + 4096);
        asm volatile("s_waitcnt vmcnt(3)" ::: "memory"); // cur tile landed; next in flight
        __builtin_amdgcn_s_barrier();
        __builtin_amdgcn_sched_barrier(0);
        const unsigned short* cA = (const unsigned short*)sA + (t & 1) * 4096;
        const unsigned short* cB = (const unsigned short*)sB + (t & 1) * 8192;
        s16x8 af[4], bf[4];
        #pragma unroll
        for (int mt = 0; mt < 4; ++mt) {
            int row = wm + mt * 16 + ln16;
            af[mt] = *(const s16x8*)(cA + row * 32 + ((q ^ ((row >> 1) & 3)) << 3));
        }
        #pragma unroll
        for (int nt = 0; nt < 4; ++nt) {
            int row = wn + nt * 16 + ln16;
            bf[nt] = *(const s16x8*)(cB + row * 32 + ((q ^ ((row >> 1) & 3)) << 3));
        }
        #pragma unroll
        for (int mt = 0; mt < 4; ++mt)
            #pragma unroll
            for (int nt = 0; nt < 4; ++nt)
                acc[mt][nt] = __builtin_amdgcn_mfma_f32_16x16x32_bf16(af[mt], bf[nt], acc[mt][nt], 0, 0, 0);
        __builtin_amdgcn_s_barrier();                    // all reads of cur buf done
    }
    // epilogue tile ch=0 (buf 1)
    asm volatile("s_waitcnt vmcnt(0)" ::: "memory");
    __builtin_amdgcn_s_barrier();
    __builtin_amdgcn_sched_barrier(0);
    {
        const unsigned short* cA = (const unsigned short*)sA + 4096;
        const unsigned short* cB = (const unsigned short*)sB + 8192;
        s16x8 af[4], bf[4];
        #pragma unroll
        for (int mt = 0; mt < 4; ++mt) {
            int row = wm + mt * 16 + ln16;
            af[mt] = *(const s16x8*)(cA + row * 32 + ((q ^ ((row >> 1) & 3)) << 3));
        }
        #pragma unroll
        for (int nt = 0; nt < 4; ++nt) {
            int row = wn + nt * 16 + ln16;
            bf[nt] = *(const s16x8*)(cB + row * 32 + ((q ^ ((row >> 1) & 3)) << 3));
        }
        #pragma unroll
        for (int mt = 0; mt < 4; ++mt)
            #pragma unroll
            for (int nt = 0; nt < 4; ++nt)
                acc[mt][nt] = __builtin_amdgcn_mfma_f32_16x16x32_bf16(af[mt], bf[nt], acc[mt][nt], 0, 0, 0);
    }

    // epilogue: +bias, relu, sumsq over s, l2norm; map compact row -> (c,i,l)
    float bv[4];
    #pragma unroll
    for (int nt = 0; nt < 4; ++nt) bv[nt] = bias[wn + nt * 16 + ln16];
    #pragma unroll
    for (int mt = 0; mt < 4; ++mt)
        #pragma unroll
        for (int j = 0; j < 4; ++j) {
            float s = 0.f;
            #pragma unroll
            for (int nt = 0; nt < 4; ++nt) {
                float v = acc[mt][nt][j] + bv[nt];
                v = fmaxf(v, 0.f);
                acc[mt][nt][j] = v;
                s += v * v;
            }
            #pragma unroll
            for (int o = 1; o < 16; o <<= 1) s += __shfl_xor(s, o, 64);
            if (ln16 == 0) atomicAdd(&s_sum[wm + mt * 16 + q * 4 + j], s);
        }
    __syncthreads();
    if (tid < 128) {
        int grow = m0 + tid;
        s_sum[tid] = (grow < Mv) ? 1.f / (sqrtf(s_sum[tid]) + 1e-8f) : 0.f;
    }
    __syncthreads();
    #pragma unroll
    for (int mt = 0; mt < 4; ++mt)
        #pragma unroll
        for (int j = 0; j < 4; ++j) {
            const int rt = wm + mt * 16 + q * 4 + j;
            const int grow = m0 + rt;
            if (grow < Mv) {
                // binary search: largest c with P[c]*64 <= grow
                int lo = 0, hi = C_N;
                while (hi - lo > 1) {
                    int mid = (lo + hi) >> 1;
                    if (P[mid] * 64 <= grow) lo = mid; else hi = mid;
                }
                const int lenc = P[lo + 1] - P[lo];
                const int rem = grow - P[lo] * 64;
                const int ii = rem / lenc;
                const int ll = rem - ii * lenc;
                const float sc = s_sum[rt];
                float* op = out + (size_t)((lo * I_N + ii) * L_N + ll) * S_N + wn;
                #pragma unroll
                for (int nt = 0; nt < 4; ++nt)
                    __builtin_nontemporal_store(acc[mt][nt][j] * sc,
                        op + nt * 16 + ln16);
            }
        }
}

extern "C" void kernel_launch(void* const* d_in, const int* in_sizes, int n_in,
                              void* d_out, int out_size, void* d_ws, size_t ws_size,
                              hipStream_t stream) {
    const float* img  = (const float*)d_in[0];
    const float* cap  = (const float*)d_in[1];
    const int*   lens = (const int*)d_in[2];
    const float* W    = (const float*)d_in[5];
    const float* bias = (const float*)d_in[6];
    float* out = (float*)d_out;
    unsigned short* ws = (unsigned short*)d_ws;
    int* P = (int*)(ws + OFF_P);

    k_convert<<<10240, 256, 0, stream>>>(img, cap, W, ws);
    k_scan<<<1, 64, 0, stream>>>(lens, P);
    k_zero<<<M_ALL / 4, 256, 0, stream>>>(lens, out);
    dim3 gridT(16, I_N);
    k_imt<<<gridT, 256, 0, stream>>>(img, ws + OFF_IMT);
    k_gram<<<I_N, 64, 0, stream>>>(ws, ws + OFF_G);

    dim3 gridP(8, I_N);   // 512 blocks; kernel decodes (oct,i) with XCD-tile remap
    k_pre<<<gridP, 512, 0, stream>>>(ws, ws + OFF_CAP, ws + OFF_IMT, ws + OFF_G,
                                     lens, P, ws + OFF_SIM);

    k_gemm3<<<M_ALL / 128, 512, 0, stream>>>(ws + OFF_SIM, ws + OFF_WT, P, bias, out);
}

// Round 11
// 457.827 us; speedup vs baseline: 2.4106x; 1.0418x over previous
//
#include <hip/hip_runtime.h>

#define C_N 64
#define I_N 64
#define R_N 36
#define L_N 40
#define D_N 1024
#define S_N 256

#define P_LD 72   // p row stride (shorts): 144 B, 16B-aligned rows

// ws layout (shorts):
#define OFF_CAP 2359296               // img end
#define OFF_WT  4980736               // cap end: wt_t [ch:32][s:256][e':32] (K-major, e'-permuted)
#define OFF_IMT 5242880               // wt end: img_t [i][d][r48]
#define OFF_SLK 8388608               // imt end: 64 zero shorts (slack)
#define OFF_SIM 8388672               // sim_t [ch:32][m:163840][e':32] bf16 (compact rows used)
#define M_ALL   (C_N * I_N * L_N)
#define CH_STRIDE ((size_t)M_ALL * 32)   // shorts per sim_t chunk plane (worst-case sized)
#define OFF_G   (OFF_SIM + 32 * CH_STRIDE)  // gram G [i][48][64] bf16
#define OFF_P   (OFF_G + I_N * 48 * 64)     // int P[65] prefix of cap_lens (cast)

typedef float f4 __attribute__((ext_vector_type(4)));
typedef short s16x8 __attribute__((ext_vector_type(8)));
typedef short s16x4 __attribute__((ext_vector_type(4)));

__device__ __forceinline__ unsigned short f2bs(float f) {
    union { float f; unsigned u; } v; v.f = f;
    unsigned r = v.u + 0x7FFFu + ((v.u >> 16) & 1u);
    return (unsigned short)(r >> 16);
}
__device__ __forceinline__ float bs2f(unsigned short s) {
    union { unsigned u; float f; } v; v.u = ((unsigned)s) << 16;
    return v.f;
}
__device__ __forceinline__ void async16(const unsigned short* g, unsigned short* l) {
    __builtin_amdgcn_global_load_lds(
        (const __attribute__((address_space(1))) unsigned int*)g,
        (__attribute__((address_space(3))) unsigned int*)l, 16, 0, 0);
}

// ---------------- K0: linear converts + folded prefix-scan (block 0) ----------------
__global__ void k_convert(const float* __restrict__ img, const float* __restrict__ cap,
                          const float* __restrict__ W, unsigned short* __restrict__ ws,
                          const int* __restrict__ lens, int* __restrict__ P) {
    int t = blockIdx.x * 256 + threadIdx.x;
    if (t < I_N * R_N * D_N) ws[t] = f2bs(img[t]);
    if (t < C_N * L_N * D_N) ws[OFF_CAP + t] = f2bs(cap[t]);
    if (t < D_N * S_N) {                       // W[d][s] -> wt_t[ch][s][e'(d)]
        int d = t >> 8, s = t & 255;
        int ch = d >> 5, wi = d & 31;
        int md = wi >> 4, r = wi & 15, q = r >> 2, j = r & 3;
        int ep = q * 8 + md * 4 + j;
        ws[OFF_WT + ((ch * 256 + s) * 32) + ep] = f2bs(W[t]);
    }
    if (t < 64) ws[OFF_SLK + t] = 0;
    if (blockIdx.x == 0 && threadIdx.x < 64) {  // wave-parallel prefix of cap_lens
        int lane = threadIdx.x;
        int v = lens[lane];
        #pragma unroll
        for (int o = 1; o < 64; o <<= 1) {
            int u = __shfl_up(v, o, 64);
            if (lane >= o) v += u;
        }
        P[lane + 1] = v;
        if (lane == 0) P[0] = 0;
    }
}

// ---------------- K0b: img [i][r][d] f32 -> imt [i][d][r48] bf16, LDS-tiled ----------
__global__ __launch_bounds__(256)
void k_imt(const float* __restrict__ img, unsigned short* __restrict__ imt) {
    __shared__ unsigned short t[64][50];
    const int i = blockIdx.y, d0 = blockIdx.x * 64;
    const int tid = threadIdx.x;
    #pragma unroll
    for (int it = 0; it < 9; ++it) {           // 36 r x 64 dc
        int e = it * 256 + tid;
        int r = e >> 6, dc = e & 63;
        t[dc][r] = f2bs(img[((size_t)i * R_N + r) * D_N + d0 + dc]);
    }
    #pragma unroll
    for (int it = 0; it < 3; ++it) {           // zero r 36..47
        int e = it * 256 + tid;
        t[e & 63][36 + (e >> 6)] = 0;
    }
    __syncthreads();
    #pragma unroll
    for (int it = 0; it < 6; ++it) {           // 64 rows x 24 dwords, contiguous
        int e = it * 256 + tid;
        int dc = e / 24, wd = e - dc * 24;
        unsigned v = (unsigned)t[dc][2 * wd] | ((unsigned)t[dc][2 * wd + 1] << 16);
        ((unsigned*)imt)[(size_t)(i * D_N + d0 + dc) * 24 + wd] = v;
    }
}

// ---------------- K0c: per-image Gram G = A.A^T, 4 waves/image + LDS reduce ------
__global__ __launch_bounds__(256)
void k_gram(const unsigned short* __restrict__ img_b, unsigned short* __restrict__ g) {
    __shared__ float sg[3][64][36];            // partials of waves 1..3
    const int i = blockIdx.x;
    const int wv = threadIdx.x >> 6, lane = threadIdx.x & 63;
    const int q = lane >> 4, ln16 = lane & 15;
    const unsigned short* ai = img_b + i * (R_N * D_N);
    unsigned short* gi = g + i * (48 * 64);
    if (wv == 3)
        for (int e = lane; e < 48 * 8; e += 64) {        // zero cols 48..63
            int r = e >> 3, wd = e & 7;
            ((unsigned*)(gi + r * 64 + 48))[wd] = 0;
        }
    f4 c[3][3] = {};
    #pragma unroll
    for (int kk = 0; kk < 8; ++kk) {           // this wave's K slice
        const int kb = (wv * 8 + kk) * 32 + q * 8;
        s16x8 af[3];
        af[0] = *(const s16x8*)(ai + ln16 * D_N + kb);
        af[1] = *(const s16x8*)(ai + (16 + ln16) * D_N + kb);
        af[2] = (ln16 < 4) ? *(const s16x8*)(ai + (32 + ln16) * D_N + kb) : (s16x8)0;
        #pragma unroll
        for (int mt = 0; mt < 3; ++mt)
            #pragma unroll
            for (int nt = 0; nt < 3; ++nt)
                c[mt][nt] = __builtin_amdgcn_mfma_f32_16x16x32_bf16(af[mt], af[nt], c[mt][nt], 0, 0, 0);
    }
    if (wv) {
        #pragma unroll
        for (int mt = 0; mt < 3; ++mt)
            #pragma unroll
            for (int nt = 0; nt < 3; ++nt)
                #pragma unroll
                for (int j = 0; j < 4; ++j)
                    sg[wv - 1][lane][(mt * 3 + nt) * 4 + j] = c[mt][nt][j];
    }
    __syncthreads();
    if (wv == 0) {
        #pragma unroll
        for (int mt = 0; mt < 3; ++mt)
            #pragma unroll
            for (int nt = 0; nt < 3; ++nt)
                #pragma unroll
                for (int j = 0; j < 4; ++j) {
                    const int idx = (mt * 3 + nt) * 4 + j;
                    float s = c[mt][nt][j] + sg[0][lane][idx] + sg[1][lane][idx] + sg[2][lane][idx];
                    gi[(mt * 16 + q * 4 + j) * 64 + nt * 16 + ln16] = f2bs(s);
                }
    }
}

// ---------------- A: one WAVE per (c,i), length-aware, compact sim rows.
// Round-11 change: sim stores are PLAIN (not nontemporal) — compacted sim
// (~210MB) fits the 256MB L3; retaining it feeds gemm3 from L3 instead of HBM.
__global__ __launch_bounds__(512, 4)
void k_pre(const unsigned short* __restrict__ img_b,
           const unsigned short* __restrict__ cap_b,
           const unsigned short* __restrict__ img_t,
           const unsigned short* __restrict__ gram,
           const int* __restrict__ lens,
           const int* __restrict__ P,
           unsigned short* __restrict__ simg) {
    __shared__ __align__(16) unsigned short s_p[8][48 * P_LD];   // 55296 B

    const int n = blockIdx.y * 8 + blockIdx.x;       // linear id; XCD = n & 7
    const int x = n & 7, m = n >> 3;
    const int i   = ((x & 3) << 4) | (m >> 2);       // 16 images per XCD
    const int oct = ((x >> 2) << 2) | (m & 3);       // 4 octets per XCD
    const int wave = threadIdx.x >> 6, lane = threadIdx.x & 63;
    const int c = oct * 8 + wave;
    const int q = lane >> 4, ln16 = lane & 15;

    const int len = lens[c];
    const int NL = (len > 32) ? 3 : (len > 16 ? 2 : 1);
    const int rowbase = P[c] * 64 + i * len;         // compact sim row base

    const unsigned short* ai = img_b + i * (R_N * D_N);          // GEMM1 A (m=r)
    const unsigned short* bc = cap_b + c * (L_N * D_N);          // GEMM1 B (n=l), sim cap
    const unsigned short* imtc = img_t + (size_t)i * D_N * 48;   // GEMM2 A (m=d,k=r)
    unsigned short* sp = &s_p[wave][0];

    // zero own p slot (covers m-pad rows 40..47 and k-pad cols 36..71)
    for (int k = lane; k < 48 * P_LD / 2; k += 64) ((unsigned*)sp)[k] = 0;

    // ---- GEMM1: attn[r][l], full K=1024; dead l-tiles (nt >= NL) skipped ----
    f4 acc[3][3] = {};
    #pragma unroll 4
    for (int ks = 0; ks < 32; ++ks) {
        const int kb = ks * 32 + q * 8;
        s16x8 af[3], bf[3];
        af[0] = *(const s16x8*)(ai + ln16 * D_N + kb);
        af[1] = *(const s16x8*)(ai + (16 + ln16) * D_N + kb);
        af[2] = (ln16 < 4) ? *(const s16x8*)(ai + (32 + ln16) * D_N + kb) : (s16x8)0;
        bf[0] = *(const s16x8*)(bc + ln16 * D_N + kb);
        bf[1] = (NL > 1) ? *(const s16x8*)(bc + (16 + ln16) * D_N + kb) : (s16x8)0;
        bf[2] = (NL > 2 && ln16 < 8) ? *(const s16x8*)(bc + (32 + ln16) * D_N + kb) : (s16x8)0;
        #pragma unroll
        for (int mt = 0; mt < 3; ++mt)
            #pragma unroll
            for (int nt = 0; nt < 3; ++nt)
                if (nt < NL)
                    acc[mt][nt] = __builtin_amdgcn_mfma_f32_16x16x32_bf16(af[mt], bf[nt], acc[mt][nt], 0, 0, 0);
    }

    // ---- leaky relu ----
    #pragma unroll
    for (int mt = 0; mt < 3; ++mt)
        #pragma unroll
        for (int nt = 0; nt < 3; ++nt)
            #pragma unroll
            for (int j = 0; j < 4; ++j) {
                float v = acc[mt][nt][j];
                acc[mt][nt][j] = (v > 0.f) ? v : 0.1f * v;
            }
    // ---- l2norm over words l per region row r ----
    #pragma unroll
    for (int mt = 0; mt < 3; ++mt)
        #pragma unroll
        for (int j = 0; j < 4; ++j) {
            float ss = 0.f;
            #pragma unroll
            for (int nt = 0; nt < 3; ++nt) ss += acc[mt][nt][j] * acc[mt][nt][j];
            #pragma unroll
            for (int o = 1; o < 16; o <<= 1) ss += __shfl_xor(ss, o, 64);
            float inv = 1.f / (sqrtf(ss) + 1e-8f);
            #pragma unroll
            for (int nt = 0; nt < 3; ++nt) acc[mt][nt][j] *= inv;
        }
    // ---- softmax over regions r per word l (live tiles only); p -> LDS ----
    #pragma unroll
    for (int nt = 0; nt < 3; ++nt) {
        if (nt < NL) {
            const int l = nt * 16 + ln16;
            float mx = -1e30f;
            #pragma unroll
            for (int mt = 0; mt < 3; ++mt)
                #pragma unroll
                for (int j = 0; j < 4; ++j) {
                    int r = mt * 16 + q * 4 + j;
                    if (r < R_N) mx = fmaxf(mx, 9.f * acc[mt][nt][j]);
                }
            mx = fmaxf(mx, __shfl_xor(mx, 16, 64));
            mx = fmaxf(mx, __shfl_xor(mx, 32, 64));
            float sum = 0.f;
            #pragma unroll
            for (int mt = 0; mt < 3; ++mt)
                #pragma unroll
                for (int j = 0; j < 4; ++j) {
                    int r = mt * 16 + q * 4 + j;
                    float e = (r < R_N) ? __expf(9.f * acc[mt][nt][j] - mx) : 0.f;
                    acc[mt][nt][j] = e;
                    sum += e;
                }
            sum += __shfl_xor(sum, 16, 64);
            sum += __shfl_xor(sum, 32, 64);
            float inv = 1.f / sum;
            #pragma unroll
            for (int mt = 0; mt < 3; ++mt)
                #pragma unroll
                for (int j = 0; j < 4; ++j) {
                    int r = mt * 16 + q * 4 + j;
                    if (r < R_N && l < L_N) sp[l * P_LD + r] = f2bs(acc[mt][nt][j] * inv);
                }
        }
    }
    // same-wave DS ordering: reads below see the writes (no barrier needed).

    // ---- GEMM2 p-fragments (dead rows are zero in sp) ----
    s16x8 paf[3][2];
    #pragma unroll
    for (int nl = 0; nl < 3; ++nl)
        #pragma unroll
        for (int ks = 0; ks < 2; ++ks)
            paf[nl][ks] = *(const s16x8*)(sp + (nl * 16 + ln16) * P_LD + ks * 32 + q * 8);

    // ---- Gram quadform: rs[l] = p_l^T G p_l (live tiles only) ----
    const unsigned short* gi = gram + i * (48 * 64);
    f4 T[3][3] = {};
    #pragma unroll
    for (int ks = 0; ks < 2; ++ks) {
        const int kb = ks * 32 + q * 8;
        s16x8 ga[3];
        #pragma unroll
        for (int mt = 0; mt < 3; ++mt)
            ga[mt] = *(const s16x8*)(gi + (mt * 16 + ln16) * 64 + kb);
        #pragma unroll
        for (int mt = 0; mt < 3; ++mt)
            #pragma unroll
            for (int nl = 0; nl < 3; ++nl)
                if (nl < NL)
                    T[mt][nl] = __builtin_amdgcn_mfma_f32_16x16x32_bf16(ga[mt], paf[nl][ks], T[mt][nl], 0, 0, 0);
    }
    float inv2[3] = {0.f, 0.f, 0.f};
    #pragma unroll
    for (int nl = 0; nl < 3; ++nl) {
        if (nl < NL) {
            const int l = nl * 16 + ln16;
            float rsl = 0.f;
            #pragma unroll
            for (int mt = 0; mt < 3; ++mt) {
                const s16x4 pv = *(const s16x4*)(sp + l * P_LD + mt * 16 + q * 4);
                #pragma unroll
                for (int j = 0; j < 4; ++j)
                    rsl += bs2f((unsigned short)pv[j]) * T[mt][nl][j];
            }
            rsl += __shfl_xor(rsl, 16, 64);
            rsl += __shfl_xor(rsl, 32, 64);
            inv2[nl] = 1.f / (sqrtf(rsl) + 1e-8f);
        }
    }

    // ---- GEMM2: sim=(wc*inv-cap)^2 -> compact rows, e'-permuted, PLAIN stores ----
    #pragma unroll 2
    for (int ch = 0; ch < 32; ++ch) {
        f4 a2[2][3] = {};
        #pragma unroll
        for (int ks = 0; ks < 2; ++ks) {
            const int kb = ks * 32 + q * 8;
            #pragma unroll
            for (int md = 0; md < 2; ++md) {
                const int drow = ch * 32 + md * 16 + ln16;
                s16x8 afr = *(const s16x8*)(imtc + drow * 48 + kb);
                #pragma unroll
                for (int nl = 0; nl < 3; ++nl)
                    if (nl < NL)
                        a2[md][nl] = __builtin_amdgcn_mfma_f32_16x16x32_bf16(afr, paf[nl][ks], a2[md][nl], 0, 0, 0);
            }
        }
        const size_t chbase = (size_t)ch * CH_STRIDE + (size_t)rowbase * 32;
        #pragma unroll
        for (int nl = 0; nl < 3; ++nl) {
            if (nl < NL) {
                const int l = nl * 16 + ln16;
                if (l < len) {
                    const float iv = inv2[nl];
                    s16x8 ov;
                    #pragma unroll
                    for (int md = 0; md < 2; ++md) {
                        const int db = ch * 32 + md * 16 + q * 4;    // global d of j=0
                        const s16x4 cv = *(const s16x4*)(bc + l * D_N + db);
                        #pragma unroll
                        for (int j = 0; j < 4; ++j) {
                            float dv = a2[md][nl][j] * iv - bs2f((unsigned short)cv[j]);
                            ov[md * 4 + j] = (short)f2bs(dv * dv);   // e' = q*8+md*4+j
                        }
                    }
                    *(s16x8*)(simg + chbase + (size_t)l * 32 + q * 8) = ov;   // plain: keep in L3
                }
            }
        }
    }
}

// ---------------- B: GEMM3 on COMPACT rows + folded zero-writer exit blocks ------
__global__ __launch_bounds__(512, 4)
void k_gemm3(const unsigned short* __restrict__ simt,
             const unsigned short* __restrict__ wtt,
             const int* __restrict__ P,
             const float* __restrict__ bias,
             float* __restrict__ out) {
    __shared__ __align__(16) unsigned short sA[2][128 * 32];   // 8 KB x2
    __shared__ __align__(16) unsigned short sB[2][256 * 32];   // 16 KB x2
    __shared__ float s_sum[128];

    const int m0 = blockIdx.x * 128;
    const int Mv = P[C_N] * 64;
    if (m0 >= Mv) {
        // zero-writer: this block zeroes masked out rows (l >= len) in its slice.
        const int nAct = (Mv + 127) >> 7;
        const int E = gridDim.x - nAct;
        const int z = blockIdx.x - nAct;
        const int r0 = (int)((long)M_ALL * z / E);
        const int r1 = (int)((long)M_ALL * (z + 1) / E);
        const int lane = threadIdx.x & 63, wv = threadIdx.x >> 6;
        f4 zz = {};
        for (int row = r0 + wv; row < r1; row += 8) {
            const int cc = row / (I_N * L_N);
            const int ll = row % L_N;
            if (ll >= P[cc + 1] - P[cc])
                __builtin_nontemporal_store(zz, (f4*)(out + (size_t)row * S_N + lane * 4));
        }
        return;
    }

    const int tid = threadIdx.x;
    const int w = tid >> 6, lane = tid & 63;
    const int ln16 = lane & 15, q = lane >> 4;
    const int wm = (w >> 2) * 64, wn = (w & 3) * 64;
    // staging: thread -> (row = tid>>2, slot = tid&3); source chunk pre-swizzled
    const int srow = tid >> 2;
    const int swz = ((tid & 3) ^ ((srow >> 1) & 3)) << 3;      // shorts
    const unsigned short* gA  = simt + ((size_t)(m0 + srow)) * 32 + swz;  // + ch*CH_STRIDE
    const unsigned short* gB0 = wtt + (size_t)srow * 32 + swz;            // + ch*8192
    const unsigned short* gB1 = wtt + (size_t)(128 + srow) * 32 + swz;
    unsigned short* const lA = (unsigned short*)sA + tid * 8;             // + buf*4096
    unsigned short* const lB = (unsigned short*)sB + tid * 8;             // + buf*8192 (+4096 for B1)

    if (tid < 128) s_sum[tid] = 0.f;

    // prologue: stage tile ch=31 into buf 0
    async16(gA + (size_t)31 * CH_STRIDE, lA);
    async16(gB0 + 31 * 8192, lB);
    async16(gB1 + 31 * 8192, lB + 4096);

    f4 acc[4][4] = {};
    #pragma unroll 1
    for (int t = 0; t < 31; ++t) {            // compute ch=31-t; prefetch ch=30-t
        const int nb = (t + 1) & 1;
        const int pch = 30 - t;
        async16(gA + (size_t)pch * CH_STRIDE, lA + nb * 4096);
        async16(gB0 + pch * 8192, lB + nb * 8192);
        async16(gB1 + pch * 8192, lB + nb * 8192 + 4096);
        asm volatile("s_waitcnt vmcnt(3)" ::: "memory"); // cur tile landed; next in flight
        __builtin_amdgcn_s_barrier();
        __builtin_amdgcn_sched_barrier(0);
        const unsigned short* cA = (const unsigned short*)sA + (t & 1) * 4096;
        const unsigned short* cB = (const unsigned short*)sB + (t & 1) * 8192;
        s16x8 af[4], bf[4];
        #pragma unroll
        for (int mt = 0; mt < 4; ++mt) {
            int row = wm + mt * 16 + ln16;
            af[mt] = *(const s16x8*)(cA + row * 32 + ((q ^ ((row >> 1) & 3)) << 3));
        }
        #pragma unroll
        for (int nt = 0; nt < 4; ++nt) {
            int row = wn + nt * 16 + ln16;
            bf[nt] = *(const s16x8*)(cB + row * 32 + ((q ^ ((row >> 1) & 3)) << 3));
        }
        #pragma unroll
        for (int mt = 0; mt < 4; ++mt)
            #pragma unroll
            for (int nt = 0; nt < 4; ++nt)
                acc[mt][nt] = __builtin_amdgcn_mfma_f32_16x16x32_bf16(af[mt], bf[nt], acc[mt][nt], 0, 0, 0);
        __builtin_amdgcn_s_barrier();                    // all reads of cur buf done
    }
    // epilogue tile ch=0 (buf 1)
    asm volatile("s_waitcnt vmcnt(0)" ::: "memory");
    __builtin_amdgcn_s_barrier();
    __builtin_amdgcn_sched_barrier(0);
    {
        const unsigned short* cA = (const unsigned short*)sA + 4096;
        const unsigned short* cB = (const unsigned short*)sB + 8192;
        s16x8 af[4], bf[4];
        #pragma unroll
        for (int mt = 0; mt < 4; ++mt) {
            int row = wm + mt * 16 + ln16;
            af[mt] = *(const s16x8*)(cA + row * 32 + ((q ^ ((row >> 1) & 3)) << 3));
        }
        #pragma unroll
        for (int nt = 0; nt < 4; ++nt) {
            int row = wn + nt * 16 + ln16;
            bf[nt] = *(const s16x8*)(cB + row * 32 + ((q ^ ((row >> 1) & 3)) << 3));
        }
        #pragma unroll
        for (int mt = 0; mt < 4; ++mt)
            #pragma unroll
            for (int nt = 0; nt < 4; ++nt)
                acc[mt][nt] = __builtin_amdgcn_mfma_f32_16x16x32_bf16(af[mt], bf[nt], acc[mt][nt], 0, 0, 0);
    }

    // epilogue: +bias, relu, sumsq over s, l2norm; map compact row -> (c,i,l)
    float bv[4];
    #pragma unroll
    for (int nt = 0; nt < 4; ++nt) bv[nt] = bias[wn + nt * 16 + ln16];
    #pragma unroll
    for (int mt = 0; mt < 4; ++mt)
        #pragma unroll
        for (int j = 0; j < 4; ++j) {
            float s = 0.f;
            #pragma unroll
            for (int nt = 0; nt < 4; ++nt) {
                float v = acc[mt][nt][j] + bv[nt];
                v = fmaxf(v, 0.f);
                acc[mt][nt][j] = v;
                s += v * v;
            }
            #pragma unroll
            for (int o = 1; o < 16; o <<= 1) s += __shfl_xor(s, o, 64);
            if (ln16 == 0) atomicAdd(&s_sum[wm + mt * 16 + q * 4 + j], s);
        }
    __syncthreads();
    if (tid < 128) {
        int grow = m0 + tid;
        s_sum[tid] = (grow < Mv) ? 1.f / (sqrtf(s_sum[tid]) + 1e-8f) : 0.f;
    }
    __syncthreads();
    #pragma unroll
    for (int mt = 0; mt < 4; ++mt)
        #pragma unroll
        for (int j = 0; j < 4; ++j) {
            const int rt = wm + mt * 16 + q * 4 + j;
            const int grow = m0 + rt;
            if (grow < Mv) {
                // binary search: largest c with P[c]*64 <= grow
                int lo = 0, hi = C_N;
                while (hi - lo > 1) {
                    int mid = (lo + hi) >> 1;
                    if (P[mid] * 64 <= grow) lo = mid; else hi = mid;
                }
                const int lenc = P[lo + 1] - P[lo];
                const int rem = grow - P[lo] * 64;
                const int ii = rem / lenc;
                const int ll = rem - ii * lenc;
                const float sc = s_sum[rt];
                float* op = out + (size_t)((lo * I_N + ii) * L_N + ll) * S_N + wn;
                #pragma unroll
                for (int nt = 0; nt < 4; ++nt)
                    __builtin_nontemporal_store(acc[mt][nt][j] * sc,
                        op + nt * 16 + ln16);
            }
        }
}

extern "C" void kernel_launch(void* const* d_in, const int* in_sizes, int n_in,
                              void* d_out, int out_size, void* d_ws, size_t ws_size,
                              hipStream_t stream) {
    const float* img  = (const float*)d_in[0];
    const float* cap  = (const float*)d_in[1];
    const int*   lens = (const int*)d_in[2];
    const float* W    = (const float*)d_in[5];
    const float* bias = (const float*)d_in[6];
    float* out = (float*)d_out;
    unsigned short* ws = (unsigned short*)d_ws;
    int* P = (int*)(ws + OFF_P);

    k_convert<<<10240, 256, 0, stream>>>(img, cap, W, ws, lens, P);
    dim3 gridT(16, I_N);
    k_imt<<<gridT, 256, 0, stream>>>(img, ws + OFF_IMT);
    k_gram<<<I_N, 256, 0, stream>>>(ws, ws + OFF_G);

    dim3 gridP(8, I_N);   // 512 blocks; kernel decodes (oct,i) with XCD-tile remap
    k_pre<<<gridP, 512, 0, stream>>>(ws, ws + OFF_CAP, ws + OFF_IMT, ws + OFF_G,
                                     lens, P, ws + OFF_SIM);

    k_gemm3<<<M_ALL / 128, 512, 0, stream>>>(ws + OFF_SIM, ws + OFF_WT, P, bias, out);
}